// Round 9
// baseline (133.572 us; speedup 1.0000x reference)
//
#include <hip/hip_runtime.h>

// GCN restructure:  deg[c] = 1 + sum_{col=c} w;  dinv = rsqrt(deg)
//   g = (X@W) * dinv[node]        (MFMA bf16; dinv applied late)
//   out[c] = relu( dinv[c] * ( g[c] + sum_{e: col=c} w_e * g[row_e] ) + b )
//
// R9: gemm1 computes UNSCALED g1 (no dinv dependency) and rides as tail
// blocks on scatter's launch (overlaps the build chain); fine_kernel scales
// its own bucket's g1 rows after computing dinv.  Both aggregation loops use
// a 4-deep gather pipeline (4 independent accs -> 4 outstanding row-gathers)
// to attack the two-level load dependency (pk -> g[pk.x]).
// Session facts: global atomic ~62B memory-side; 64M LDS atomics = 445us;
// f32-VALU GEMM latency-bound -> MFMA; agg1+gemm2 fused in LDS.

#define BNODES 128
#define LB 7
#define MAXBKT 1024
#define EPT 16
#define EPB (256 * EPT)

typedef __attribute__((ext_vector_type(8))) short bf16x8;
typedef __attribute__((ext_vector_type(4))) float f32x4;

__device__ __forceinline__ unsigned short f2bf(float f) {
    unsigned u = __float_as_uint(f);
    u = (u + 0x7FFF + ((u >> 16) & 1)) >> 16;   // rtne
    return (unsigned short)u;
}
__device__ __forceinline__ float bf2f(unsigned short h) {
    return __uint_as_float(((unsigned)h) << 16);
}

__device__ __forceinline__ int waveIncScan(int v, int lane) {
    #pragma unroll
    for (int d = 1; d < 64; d <<= 1) {
        int u = __shfl_up(v, d, 64);
        if (lane >= d) v += u;
    }
    return v;
}

__device__ __forceinline__ int blockIncScan(int v, int t, int* wt) {
    int lane = t & 63, w = t >> 6;
    int s = waveIncScan(v, lane);
    if (lane == 63) wt[w] = s;
    __syncthreads();
    int add = 0;
    #pragma unroll
    for (int i = 0; i < 3; ++i) if (i < w) add += wt[i];
    return s + add;
}

// ---- hist (+ weight transpose in tail blocks) ----------------------------

__global__ __launch_bounds__(256) void hist_kernel(
    const int* __restrict__ col, int* __restrict__ H, int E, int NBKT,
    const float* __restrict__ W1, const float* __restrict__ W2,
    unsigned short* __restrict__ WT1, unsigned short* __restrict__ WT2, int NEB)
{
    int t = threadIdx.x, blk = blockIdx.x;
    if (blk >= NEB) {                       // wtconv tail blocks
        int i = (blk - NEB) * 256 + t;
        if (i < 64 * 128) {
            int c = i >> 7, k = i & 127;    // WT1[c][k] = W1[k][c]
            WT1[i] = f2bf(W1[k * 64 + c]);
        } else if (i < 64 * 128 + 64 * 64) {
            int j = i - 64 * 128;
            int c = j >> 6, k = j & 63;     // WT2[c][k] = W2[k][c]
            WT2[j] = f2bf(W2[k * 64 + c]);
        }
        return;
    }
    __shared__ int h[MAXBKT];
    for (int b = t; b < NBKT; b += 256) h[b] = 0;
    __syncthreads();
    int base = blk * EPB;
    #pragma unroll
    for (int i = 0; i < EPT; ++i) {
        int e = base + i * 256 + t;
        if (e < E) atomicAdd(&h[col[e] >> LB], 1);
    }
    __syncthreads();
    for (int b = t; b < NBKT; b += 256) H[blk * NBKT + b] = h[b];
}

__global__ __launch_bounds__(256) void rowscan_kernel(
    int* __restrict__ H, int* __restrict__ rowSum, int NEB, int NBKT)
{
    __shared__ int wt[4];
    int b = blockIdx.x, t = threadIdx.x;
    int v = (t < NEB) ? H[t * NBKT + b] : 0;
    int incl = blockIncScan(v, t, wt);
    if (t < NEB) H[t * NBKT + b] = incl - v;
    if (t == 255) rowSum[b] = incl;
}

__global__ __launch_bounds__(256) void bktscan_kernel(
    const int* __restrict__ rowSum, int* __restrict__ bktStart, int NBKT)
{
    __shared__ int wt[4];
    int t = threadIdx.x;
    int v[4]; int sum = 0;
    #pragma unroll
    for (int k = 0; k < 4; ++k) {
        int i = t * 4 + k;
        v[k] = (i < NBKT) ? rowSum[i] : 0;
        sum += v[k];
    }
    int incl = blockIncScan(sum, t, wt);
    int excl = incl - sum;
    #pragma unroll
    for (int k = 0; k < 4; ++k) {
        int i = t * 4 + k;
        if (i < NBKT) bktStart[i] = excl;
        excl += v[k];
    }
    if (t == 255) bktStart[NBKT] = incl;
}

// ---- merged scatter + layer-1 MFMA GEMM (unscaled) -----------------------
// blocks [0, NEB): coarse scatter (LDS cursors, zero global atomics)
// blocks [NEB, NEB+nbG): g1U[node,:] = bf16( X[node,:] @ W1 )  (64x64 tile)
__global__ __launch_bounds__(256) void scatter_gemm_kernel(
    const int* __restrict__ row, const int* __restrict__ col,
    const float* __restrict__ w, const int* __restrict__ H,
    const int* __restrict__ bktStart, int2* __restrict__ sedge1,
    int E, int NBKT, int NEB,
    const float* __restrict__ X, const unsigned short* __restrict__ WT,
    unsigned short* __restrict__ G, int n)
{
    __shared__ char smem[64 * 256 * 2];        // 32 KB (gemm); scatter uses 4 KB
    const int t = threadIdx.x;
    const int blk = blockIdx.x;

    if (blk < NEB) {
        // ---------------- scatter role ----------------
        int* cur = (int*)smem;
        for (int b = t; b < NBKT; b += 256) cur[b] = bktStart[b] + H[blk * NBKT + b];
        __syncthreads();
        int base = blk * EPB;
        #pragma unroll
        for (int i = 0; i < EPT; ++i) {
            int e = base + i * 256 + t;
            if (e < E) {
                int c = col[e];
                int b = c >> LB;
                int pos = atomicAdd(&cur[b], 1);      // LDS atomic
                int2 pk;
                pk.x = row[e] | ((c & (BNODES - 1)) << 20);
                pk.y = __float_as_int(w[e]);
                sedge1[pos] = pk;
            }
        }
        return;
    }

    // ---------------- gemm role (K=128, f32 in, unscaled out) ----------------
    constexpr int K = 128, ROWB = 256, SLOTS = 16, CPR = 32;
    char* xs = smem;
    char* ws = smem + 64 * ROWB;
    const int nodeBase = (blk - NEB) * 64;

    for (int q = t; q < 64 * SLOTS; q += 256) {
        int r = q / SLOTS, s = q % SLOTS;
        uint4 v = *(const uint4*)(WT + r * K + s * 8);
        *(uint4*)(ws + r * ROWB + ((s ^ (r & 7)) * 16)) = v;
    }
    for (int q = t; q < 64 * CPR; q += 256) {
        int r = q / CPR, c = q % CPR;
        int node = nodeBase + r;
        float4 v = make_float4(0.f, 0.f, 0.f, 0.f);
        if (node < n) v = *(const float4*)(X + (size_t)node * K + c * 4);
        ushort4 h;
        h.x = f2bf(v.x); h.y = f2bf(v.y); h.z = f2bf(v.z); h.w = f2bf(v.w);
        *(ushort4*)(xs + r * ROWB + (((c >> 1) ^ (r & 7)) * 16) + (c & 1) * 8) = h;
    }
    __syncthreads();

    const int lane = t & 63;
    const int wv = t >> 6;
    const int lr = lane & 15;
    const int lk = lane >> 4;
    const int arow = (wv << 4) + lr;

    f32x4 acc[4] = {};
    #pragma unroll
    for (int kb = 0; kb < 4; ++kb) {
        int s = kb * 4 + lk;
        bf16x8 a = *(bf16x8*)(xs + arow * ROWB + ((s ^ (arow & 7)) * 16));
        #pragma unroll
        for (int cb = 0; cb < 4; ++cb) {
            int c = cb * 16 + lr;
            bf16x8 b = *(bf16x8*)(ws + c * ROWB + ((s ^ (c & 7)) * 16));
            acc[cb] = __builtin_amdgcn_mfma_f32_16x16x32_bf16(a, b, acc[cb], 0, 0, 0);
        }
    }

    int rowbase = nodeBase + (wv << 4) + (lk << 2);
    #pragma unroll
    for (int j = 0; j < 4; ++j) {
        int node = rowbase + j;
        if (node >= n) continue;
        #pragma unroll
        for (int cb = 0; cb < 4; ++cb)
            G[(size_t)node * 64 + cb * 16 + lr] = f2bf(acc[cb][j]);
    }
}

// ---- fine: bucket -> per-node CSR + dinv + scale own g1 rows -------------
__global__ __launch_bounds__(256) void fine_kernel(
    const int2* __restrict__ sedge1, const int* __restrict__ bktStart,
    int2* __restrict__ sedge2, int* __restrict__ nodeStart,
    int* __restrict__ nodeCnt, float* __restrict__ dinv,
    unsigned short* __restrict__ g1, int n)
{
    __shared__ int cnt[BNODES];
    __shared__ float wsum[BNODES];
    __shared__ int off[BNODES];
    __shared__ int cur[BNODES];
    __shared__ float dloc[BNODES];
    __shared__ int wt[4];
    int b = blockIdx.x, t = threadIdx.x;
    if (t < BNODES) { cnt[t] = 0; wsum[t] = 1.0f; }
    __syncthreads();
    int s = bktStart[b], e = bktStart[b + 1];
    for (int j = s + t; j < e; j += 256) {
        int2 pk = sedge1[j];
        int ld = pk.x >> 20;
        atomicAdd(&cnt[ld], 1);
        atomicAdd(&wsum[ld], __int_as_float(pk.y));
    }
    __syncthreads();
    int v = (t < BNODES) ? cnt[t] : 0;
    int incl = blockIncScan(v, t, wt);                 // has __syncthreads
    if (t < BNODES) {
        off[t] = s + incl - v;
        cur[t] = s + incl - v;
        dloc[t] = rsqrtf(wsum[t]);
    }
    __syncthreads();
    int node = b * BNODES + t;
    if (t < BNODES && node < n) {
        nodeStart[node] = off[t];
        nodeCnt[node] = cnt[t];
        dinv[node] = dloc[t];
    }
    // scatter bucket edges to per-node slots
    for (int j = s + t; j < e; j += 256) {
        int2 pk = sedge1[j];
        int ld = pk.x >> 20;
        int pos = atomicAdd(&cur[ld], 1);              // LDS atomic
        sedge2[pos] = make_int2(pk.x & 0xFFFFF, pk.y);
    }
    // scale own bucket's g1 rows by dinv (g1 was written unscaled)
    for (int q = t; q < BNODES * 8; q += 256) {
        int r = q >> 3, cc = q & 7;
        int nd = b * BNODES + r;
        if (nd >= n) continue;
        float dv = dloc[r];
        size_t offb = (size_t)nd * 64 + cc * 8;
        ushort4 u0 = *(const ushort4*)(g1 + offb);
        ushort4 u1 = *(const ushort4*)(g1 + offb + 4);
        u0.x = f2bf(bf2f(u0.x) * dv); u0.y = f2bf(bf2f(u0.y) * dv);
        u0.z = f2bf(bf2f(u0.z) * dv); u0.w = f2bf(bf2f(u0.w) * dv);
        u1.x = f2bf(bf2f(u1.x) * dv); u1.y = f2bf(bf2f(u1.y) * dv);
        u1.z = f2bf(bf2f(u1.z) * dv); u1.w = f2bf(bf2f(u1.w) * dv);
        *(ushort4*)(g1 + offb) = u0;
        *(ushort4*)(g1 + offb + 4) = u1;
    }
}

// ---- 4-deep gather accumulate helper (16 lanes/node, feature slice p) ----
__device__ __forceinline__ float4 gather_accum(
    const unsigned short* __restrict__ G, const int2* __restrict__ eb,
    int m, int p, float4 a0)
{
    float4 a1 = make_float4(0.f, 0.f, 0.f, 0.f);
    float4 a2 = make_float4(0.f, 0.f, 0.f, 0.f);
    float4 a3 = make_float4(0.f, 0.f, 0.f, 0.f);
    int j = 0;
    for (; j + 3 < m; j += 4) {
        int2 pk0 = eb[j], pk1 = eb[j + 1], pk2 = eb[j + 2], pk3 = eb[j + 3];
        ushort4 g0 = *(const ushort4*)&G[(size_t)pk0.x * 64 + p * 4];
        ushort4 g1 = *(const ushort4*)&G[(size_t)pk1.x * 64 + p * 4];
        ushort4 g2 = *(const ushort4*)&G[(size_t)pk2.x * 64 + p * 4];
        ushort4 g3 = *(const ushort4*)&G[(size_t)pk3.x * 64 + p * 4];
        float w0 = __int_as_float(pk0.y), w1 = __int_as_float(pk1.y);
        float w2 = __int_as_float(pk2.y), w3 = __int_as_float(pk3.y);
        a0.x = fmaf(w0, bf2f(g0.x), a0.x); a0.y = fmaf(w0, bf2f(g0.y), a0.y);
        a0.z = fmaf(w0, bf2f(g0.z), a0.z); a0.w = fmaf(w0, bf2f(g0.w), a0.w);
        a1.x = fmaf(w1, bf2f(g1.x), a1.x); a1.y = fmaf(w1, bf2f(g1.y), a1.y);
        a1.z = fmaf(w1, bf2f(g1.z), a1.z); a1.w = fmaf(w1, bf2f(g1.w), a1.w);
        a2.x = fmaf(w2, bf2f(g2.x), a2.x); a2.y = fmaf(w2, bf2f(g2.y), a2.y);
        a2.z = fmaf(w2, bf2f(g2.z), a2.z); a2.w = fmaf(w2, bf2f(g2.w), a2.w);
        a3.x = fmaf(w3, bf2f(g3.x), a3.x); a3.y = fmaf(w3, bf2f(g3.y), a3.y);
        a3.z = fmaf(w3, bf2f(g3.z), a3.z); a3.w = fmaf(w3, bf2f(g3.w), a3.w);
    }
    for (; j < m; ++j) {
        int2 pk = eb[j];
        float w = __int_as_float(pk.y);
        ushort4 g = *(const ushort4*)&G[(size_t)pk.x * 64 + p * 4];
        a0.x = fmaf(w, bf2f(g.x), a0.x); a0.y = fmaf(w, bf2f(g.y), a0.y);
        a0.z = fmaf(w, bf2f(g.z), a0.z); a0.w = fmaf(w, bf2f(g.w), a0.w);
    }
    a0.x += a1.x + a2.x + a3.x;
    a0.y += a1.y + a2.y + a3.y;
    a0.z += a1.z + a2.z + a3.z;
    a0.w += a1.w + a2.w + a3.w;
    return a0;
}

// ---- FUSED agg1 + gemm2 (act in LDS only) --------------------------------
__global__ __launch_bounds__(256) void aggmm_kernel(
    const unsigned short* __restrict__ G1, const int2* __restrict__ sedge2,
    const int* __restrict__ nodeStart, const int* __restrict__ nodeCnt,
    const float* __restrict__ dinv, const float* __restrict__ bias,
    const unsigned short* __restrict__ WT2, unsigned short* __restrict__ G2, int n)
{
    constexpr int ROWB = 128;
    __shared__ char smem[64 * ROWB * 2]; // act | ws  (16 KB)
    char* xs = smem;
    char* ws = smem + 64 * ROWB;
    const int tid = threadIdx.x;
    const int nodeBase = blockIdx.x * 64;

    for (int q = tid; q < 64 * 8; q += 256) {
        int r = q >> 3, s = q & 7;
        uint4 v = *(const uint4*)(WT2 + r * 64 + s * 8);
        *(uint4*)(ws + r * ROWB + ((s ^ (r & 7)) * 16)) = v;
    }

    int p = tid & 15;
    float4 bb = *(const float4*)&bias[p * 4];
    #pragma unroll
    for (int pass = 0; pass < 4; ++pass) {
        int r = pass * 16 + (tid >> 4);
        int node = nodeBase + r;
        float4 o = make_float4(0.f, 0.f, 0.f, 0.f);
        if (node < n) {
            ushort4 sv = *(const ushort4*)&G1[(size_t)node * 64 + p * 4];
            float4 a = make_float4(bf2f(sv.x), bf2f(sv.y), bf2f(sv.z), bf2f(sv.w));
            int s = nodeStart[node];
            a = gather_accum(G1, sedge2 + s, nodeCnt[node], p, a);
            float di = dinv[node];
            o.x = fmaxf(fmaf(di, a.x, bb.x), 0.f);
            o.y = fmaxf(fmaf(di, a.y, bb.y), 0.f);
            o.z = fmaxf(fmaf(di, a.z, bb.z), 0.f);
            o.w = fmaxf(fmaf(di, a.w, bb.w), 0.f);
        }
        ushort4 h;
        h.x = f2bf(o.x); h.y = f2bf(o.y); h.z = f2bf(o.z); h.w = f2bf(o.w);
        *(ushort4*)(xs + r * ROWB + (((p >> 1) ^ (r & 7)) * 16) + (p & 1) * 8) = h;
    }
    __syncthreads();

    const int lane = tid & 63;
    const int w = tid >> 6;
    const int lr = lane & 15;
    const int lk = lane >> 4;
    const int arow = (w << 4) + lr;

    f32x4 acc[4] = {};
    #pragma unroll
    for (int kb = 0; kb < 2; ++kb) {
        int s = kb * 4 + lk;
        bf16x8 a = *(bf16x8*)(xs + arow * ROWB + ((s ^ (arow & 7)) * 16));
        #pragma unroll
        for (int cb = 0; cb < 4; ++cb) {
            int c = cb * 16 + lr;
            bf16x8 b = *(bf16x8*)(ws + c * ROWB + ((s ^ (c & 7)) * 16));
            acc[cb] = __builtin_amdgcn_mfma_f32_16x16x32_bf16(a, b, acc[cb], 0, 0, 0);
        }
    }

    int rowbase = nodeBase + (w << 4) + (lk << 2);
    #pragma unroll
    for (int j = 0; j < 4; ++j) {
        int node = rowbase + j;
        if (node >= n) continue;
        float dv = dinv[node];
        #pragma unroll
        for (int cb = 0; cb < 4; ++cb)
            G2[(size_t)node * 64 + cb * 16 + lr] = f2bf(acc[cb][j] * dv);
    }
}

// ---- final aggregation (f32 out) -----------------------------------------
__global__ __launch_bounds__(256) void agg_kernel(
    const unsigned short* __restrict__ G, const int2* __restrict__ sedge2,
    const int* __restrict__ nodeStart, const int* __restrict__ nodeCnt,
    const float* __restrict__ dinv, const float* __restrict__ bias,
    float* __restrict__ OUT, int n)
{
    int t = blockIdx.x * blockDim.x + threadIdx.x;
    if (t >= n * 16) return;
    int node = t >> 4, p = t & 15;

    ushort4 sv = *(const ushort4*)&G[(size_t)node * 64 + p * 4];
    float4 a = make_float4(bf2f(sv.x), bf2f(sv.y), bf2f(sv.z), bf2f(sv.w));
    int s = nodeStart[node];
    a = gather_accum(G, sedge2 + s, nodeCnt[node], p, a);

    float di = dinv[node];
    float4 bb = *(const float4*)&bias[p * 4];
    float4 o;
    o.x = fmaxf(fmaf(di, a.x, bb.x), 0.f);
    o.y = fmaxf(fmaf(di, a.y, bb.y), 0.f);
    o.z = fmaxf(fmaf(di, a.z, bb.z), 0.f);
    o.w = fmaxf(fmaf(di, a.w, bb.w), 0.f);
    *(float4*)&OUT[(size_t)node * 64 + p * 4] = o;
}

extern "C" void kernel_launch(void* const* d_in, const int* in_sizes, int n_in,
                              void* d_out, int out_size, void* d_ws, size_t ws_size,
                              hipStream_t stream) {
    const float* x     = (const float*)d_in[0];
    const int*   eidx  = (const int*)d_in[1];
    const float* eattr = (const float*)d_in[2];
    const float* W1    = (const float*)d_in[3];
    const float* b1    = (const float*)d_in[4];
    const float* W2    = (const float*)d_in[5];
    const float* b2    = (const float*)d_in[6];
    float* out = (float*)d_out;

    const int n = in_sizes[0] / 128;
    const int E = in_sizes[2];
    const int* row = eidx;
    const int* col = eidx + E;

    const int NBKT = (n + BNODES - 1) / BNODES;    // 782
    const int NEB  = (E + EPB - 1) / EPB;          // 245 (<=256 required)

    // ws (~45 MB): sedge1[E] | sedge2[E] | g1[n*64]u16 | g2[n*64]u16 |
    //   WT1 | WT2 | dinv[n] | nodeStart[n] | nodeCnt[n] | H | rowSum | bktStart
    int2*  sedge1 = (int2*)d_ws;
    int2*  sedge2 = sedge1 + (size_t)E;
    unsigned short* g1 = (unsigned short*)(sedge2 + (size_t)E);
    unsigned short* g2 = g1 + (size_t)n * 64;
    unsigned short* WT1 = g2 + (size_t)n * 64;
    unsigned short* WT2 = WT1 + 64 * 128;
    float* dinv      = (float*)(WT2 + 64 * 64);
    int*   nodeStart = (int*)(dinv + n);
    int*   nodeCnt   = nodeStart + n;
    int*   H         = nodeCnt + n;
    int*   rowSum    = H + (size_t)NEB * NBKT;
    int*   bktStart  = rowSum + NBKT;

    const int nbG = (n + 63) / 64;
    const int nbA = (int)(((size_t)n * 16 + 255) / 256);

    // ---- build + layer-1 GEMM (gemm1 rides on scatter's launch)
    hist_kernel<<<NEB + 48, 256, 0, stream>>>(col, H, E, NBKT, W1, W2, WT1, WT2, NEB);
    rowscan_kernel<<<NBKT, 256, 0, stream>>>(H, rowSum, NEB, NBKT);
    bktscan_kernel<<<1, 256, 0, stream>>>(rowSum, bktStart, NBKT);
    scatter_gemm_kernel<<<NEB + nbG, 256, 0, stream>>>(
        row, col, eattr, H, bktStart, sedge1, E, NBKT, NEB, x, WT1, g1, n);
    fine_kernel<<<NBKT, 256, 0, stream>>>(sedge1, bktStart, sedge2, nodeStart,
                                          nodeCnt, dinv, g1, n);

    // ---- fused agg1 + gemm2: g2 = (relu(agg(g1))@W2)*dinv  (bf16)
    aggmm_kernel<<<nbG, 256, 0, stream>>>(g1, sedge2, nodeStart, nodeCnt, dinv, b1, WT2, g2, n);
    // ---- final aggregation -> d_out (f32)
    agg_kernel<<<nbA, 256, 0, stream>>>(g2, sedge2, nodeStart, nodeCnt, dinv, b2, out, n);
}

// Round 10
// 126.377 us; speedup vs baseline: 1.0569x; 1.0569x over previous
//
#include <hip/hip_runtime.h>

// GCN restructure:  deg[c] = 1 + sum_{col=c} w;  dinv = rsqrt(deg)
//   g = (X@W) * dinv[node]        (MFMA bf16; dinv applied late)
//   out[c] = relu( dinv[c] * ( g[c] + sum_{e: col=c} w_e * g[row_e] ) + b )
//
// R10: aggmm re-tiled to 32 nodes/block (3125 blocks -> wave-capped occupancy,
// was grid-limited at 6 blocks/CU = 34%); gather loops reverted to the proven
// 2-deep pipeline (R9's 4-deep was a measured regression).  scatter+gemm1
// merged launch, fine-scaled g1, CSR build unchanged.
// Session facts: global atomic ~62B memory-side; 64M LDS atomics = 445us;
// f32-VALU GEMM latency-bound -> MFMA; agg kernels latency-bound on the
// 2-level gather (descriptor -> row), occupancy is the lever.

#define BNODES 128
#define LB 7
#define MAXBKT 1024
#define EPT 16
#define EPB (256 * EPT)

typedef __attribute__((ext_vector_type(8))) short bf16x8;
typedef __attribute__((ext_vector_type(4))) float f32x4;

__device__ __forceinline__ unsigned short f2bf(float f) {
    unsigned u = __float_as_uint(f);
    u = (u + 0x7FFF + ((u >> 16) & 1)) >> 16;   // rtne
    return (unsigned short)u;
}
__device__ __forceinline__ float bf2f(unsigned short h) {
    return __uint_as_float(((unsigned)h) << 16);
}

__device__ __forceinline__ int waveIncScan(int v, int lane) {
    #pragma unroll
    for (int d = 1; d < 64; d <<= 1) {
        int u = __shfl_up(v, d, 64);
        if (lane >= d) v += u;
    }
    return v;
}

__device__ __forceinline__ int blockIncScan(int v, int t, int* wt) {
    int lane = t & 63, w = t >> 6;
    int s = waveIncScan(v, lane);
    if (lane == 63) wt[w] = s;
    __syncthreads();
    int add = 0;
    #pragma unroll
    for (int i = 0; i < 3; ++i) if (i < w) add += wt[i];
    return s + add;
}

// 2-deep gather accumulate (16 lanes/node, feature slice p) — proven in R8.
__device__ __forceinline__ float4 gather2(
    const unsigned short* __restrict__ G, const int2* __restrict__ eb,
    int m, int p, float4 a0)
{
    float4 a1 = make_float4(0.f, 0.f, 0.f, 0.f);
    int j = 0;
    for (; j + 1 < m; j += 2) {
        int2 pk0 = eb[j];
        int2 pk1 = eb[j + 1];
        float w0 = __int_as_float(pk0.y);
        float w1 = __int_as_float(pk1.y);
        ushort4 g0 = *(const ushort4*)&G[(size_t)pk0.x * 64 + p * 4];
        ushort4 g1 = *(const ushort4*)&G[(size_t)pk1.x * 64 + p * 4];
        a0.x = fmaf(w0, bf2f(g0.x), a0.x); a0.y = fmaf(w0, bf2f(g0.y), a0.y);
        a0.z = fmaf(w0, bf2f(g0.z), a0.z); a0.w = fmaf(w0, bf2f(g0.w), a0.w);
        a1.x = fmaf(w1, bf2f(g1.x), a1.x); a1.y = fmaf(w1, bf2f(g1.y), a1.y);
        a1.z = fmaf(w1, bf2f(g1.z), a1.z); a1.w = fmaf(w1, bf2f(g1.w), a1.w);
    }
    if (j < m) {
        int2 pk = eb[j];
        float w = __int_as_float(pk.y);
        ushort4 g = *(const ushort4*)&G[(size_t)pk.x * 64 + p * 4];
        a0.x = fmaf(w, bf2f(g.x), a0.x); a0.y = fmaf(w, bf2f(g.y), a0.y);
        a0.z = fmaf(w, bf2f(g.z), a0.z); a0.w = fmaf(w, bf2f(g.w), a0.w);
    }
    a0.x += a1.x; a0.y += a1.y; a0.z += a1.z; a0.w += a1.w;
    return a0;
}

// ---- hist (+ weight transpose in tail blocks) ----------------------------

__global__ __launch_bounds__(256) void hist_kernel(
    const int* __restrict__ col, int* __restrict__ H, int E, int NBKT,
    const float* __restrict__ W1, const float* __restrict__ W2,
    unsigned short* __restrict__ WT1, unsigned short* __restrict__ WT2, int NEB)
{
    int t = threadIdx.x, blk = blockIdx.x;
    if (blk >= NEB) {
        int i = (blk - NEB) * 256 + t;
        if (i < 64 * 128) {
            int c = i >> 7, k = i & 127;
            WT1[i] = f2bf(W1[k * 64 + c]);
        } else if (i < 64 * 128 + 64 * 64) {
            int j = i - 64 * 128;
            int c = j >> 6, k = j & 63;
            WT2[j] = f2bf(W2[k * 64 + c]);
        }
        return;
    }
    __shared__ int h[MAXBKT];
    for (int b = t; b < NBKT; b += 256) h[b] = 0;
    __syncthreads();
    int base = blk * EPB;
    #pragma unroll
    for (int i = 0; i < EPT; ++i) {
        int e = base + i * 256 + t;
        if (e < E) atomicAdd(&h[col[e] >> LB], 1);
    }
    __syncthreads();
    for (int b = t; b < NBKT; b += 256) H[blk * NBKT + b] = h[b];
}

__global__ __launch_bounds__(256) void rowscan_kernel(
    int* __restrict__ H, int* __restrict__ rowSum, int NEB, int NBKT)
{
    __shared__ int wt[4];
    int b = blockIdx.x, t = threadIdx.x;
    int v = (t < NEB) ? H[t * NBKT + b] : 0;
    int incl = blockIncScan(v, t, wt);
    if (t < NEB) H[t * NBKT + b] = incl - v;
    if (t == 255) rowSum[b] = incl;
}

__global__ __launch_bounds__(256) void bktscan_kernel(
    const int* __restrict__ rowSum, int* __restrict__ bktStart, int NBKT)
{
    __shared__ int wt[4];
    int t = threadIdx.x;
    int v[4]; int sum = 0;
    #pragma unroll
    for (int k = 0; k < 4; ++k) {
        int i = t * 4 + k;
        v[k] = (i < NBKT) ? rowSum[i] : 0;
        sum += v[k];
    }
    int incl = blockIncScan(sum, t, wt);
    int excl = incl - sum;
    #pragma unroll
    for (int k = 0; k < 4; ++k) {
        int i = t * 4 + k;
        if (i < NBKT) bktStart[i] = excl;
        excl += v[k];
    }
    if (t == 255) bktStart[NBKT] = incl;
}

// ---- merged scatter + layer-1 MFMA GEMM (unscaled) -----------------------
__global__ __launch_bounds__(256) void scatter_gemm_kernel(
    const int* __restrict__ row, const int* __restrict__ col,
    const float* __restrict__ w, const int* __restrict__ H,
    const int* __restrict__ bktStart, int2* __restrict__ sedge1,
    int E, int NBKT, int NEB,
    const float* __restrict__ X, const unsigned short* __restrict__ WT,
    unsigned short* __restrict__ G, int n)
{
    __shared__ char smem[64 * 256 * 2];
    const int t = threadIdx.x;
    const int blk = blockIdx.x;

    if (blk < NEB) {
        int* cur = (int*)smem;
        for (int b = t; b < NBKT; b += 256) cur[b] = bktStart[b] + H[blk * NBKT + b];
        __syncthreads();
        int base = blk * EPB;
        #pragma unroll
        for (int i = 0; i < EPT; ++i) {
            int e = base + i * 256 + t;
            if (e < E) {
                int c = col[e];
                int b = c >> LB;
                int pos = atomicAdd(&cur[b], 1);      // LDS atomic
                int2 pk;
                pk.x = row[e] | ((c & (BNODES - 1)) << 20);
                pk.y = __float_as_int(w[e]);
                sedge1[pos] = pk;
            }
        }
        return;
    }

    constexpr int K = 128, ROWB = 256, SLOTS = 16, CPR = 32;
    char* xs = smem;
    char* ws = smem + 64 * ROWB;
    const int nodeBase = (blk - NEB) * 64;

    for (int q = t; q < 64 * SLOTS; q += 256) {
        int r = q / SLOTS, s = q % SLOTS;
        uint4 v = *(const uint4*)(WT + r * K + s * 8);
        *(uint4*)(ws + r * ROWB + ((s ^ (r & 7)) * 16)) = v;
    }
    for (int q = t; q < 64 * CPR; q += 256) {
        int r = q / CPR, c = q % CPR;
        int node = nodeBase + r;
        float4 v = make_float4(0.f, 0.f, 0.f, 0.f);
        if (node < n) v = *(const float4*)(X + (size_t)node * K + c * 4);
        ushort4 h;
        h.x = f2bf(v.x); h.y = f2bf(v.y); h.z = f2bf(v.z); h.w = f2bf(v.w);
        *(ushort4*)(xs + r * ROWB + (((c >> 1) ^ (r & 7)) * 16) + (c & 1) * 8) = h;
    }
    __syncthreads();

    const int lane = t & 63;
    const int wv = t >> 6;
    const int lr = lane & 15;
    const int lk = lane >> 4;
    const int arow = (wv << 4) + lr;

    f32x4 acc[4] = {};
    #pragma unroll
    for (int kb = 0; kb < 4; ++kb) {
        int s = kb * 4 + lk;
        bf16x8 a = *(bf16x8*)(xs + arow * ROWB + ((s ^ (arow & 7)) * 16));
        #pragma unroll
        for (int cb = 0; cb < 4; ++cb) {
            int c = cb * 16 + lr;
            bf16x8 b = *(bf16x8*)(ws + c * ROWB + ((s ^ (c & 7)) * 16));
            acc[cb] = __builtin_amdgcn_mfma_f32_16x16x32_bf16(a, b, acc[cb], 0, 0, 0);
        }
    }

    int rowbase = nodeBase + (wv << 4) + (lk << 2);
    #pragma unroll
    for (int j = 0; j < 4; ++j) {
        int node = rowbase + j;
        if (node >= n) continue;
        #pragma unroll
        for (int cb = 0; cb < 4; ++cb)
            G[(size_t)node * 64 + cb * 16 + lr] = f2bf(acc[cb][j]);
    }
}

// ---- fine: bucket -> per-node CSR + dinv + scale own g1 rows -------------
__global__ __launch_bounds__(256) void fine_kernel(
    const int2* __restrict__ sedge1, const int* __restrict__ bktStart,
    int2* __restrict__ sedge2, int* __restrict__ nodeStart,
    int* __restrict__ nodeCnt, float* __restrict__ dinv,
    unsigned short* __restrict__ g1, int n)
{
    __shared__ int cnt[BNODES];
    __shared__ float wsum[BNODES];
    __shared__ int off[BNODES];
    __shared__ int cur[BNODES];
    __shared__ float dloc[BNODES];
    __shared__ int wt[4];
    int b = blockIdx.x, t = threadIdx.x;
    if (t < BNODES) { cnt[t] = 0; wsum[t] = 1.0f; }
    __syncthreads();
    int s = bktStart[b], e = bktStart[b + 1];
    for (int j = s + t; j < e; j += 256) {
        int2 pk = sedge1[j];
        int ld = pk.x >> 20;
        atomicAdd(&cnt[ld], 1);
        atomicAdd(&wsum[ld], __int_as_float(pk.y));
    }
    __syncthreads();
    int v = (t < BNODES) ? cnt[t] : 0;
    int incl = blockIncScan(v, t, wt);
    if (t < BNODES) {
        off[t] = s + incl - v;
        cur[t] = s + incl - v;
        dloc[t] = rsqrtf(wsum[t]);
    }
    __syncthreads();
    int node = b * BNODES + t;
    if (t < BNODES && node < n) {
        nodeStart[node] = off[t];
        nodeCnt[node] = cnt[t];
        dinv[node] = dloc[t];
    }
    for (int j = s + t; j < e; j += 256) {
        int2 pk = sedge1[j];
        int ld = pk.x >> 20;
        int pos = atomicAdd(&cur[ld], 1);
        sedge2[pos] = make_int2(pk.x & 0xFFFFF, pk.y);
    }
    for (int q = t; q < BNODES * 8; q += 256) {
        int r = q >> 3, cc = q & 7;
        int nd = b * BNODES + r;
        if (nd >= n) continue;
        float dv = dloc[r];
        size_t offb = (size_t)nd * 64 + cc * 8;
        ushort4 u0 = *(const ushort4*)(g1 + offb);
        ushort4 u1 = *(const ushort4*)(g1 + offb + 4);
        u0.x = f2bf(bf2f(u0.x) * dv); u0.y = f2bf(bf2f(u0.y) * dv);
        u0.z = f2bf(bf2f(u0.z) * dv); u0.w = f2bf(bf2f(u0.w) * dv);
        u1.x = f2bf(bf2f(u1.x) * dv); u1.y = f2bf(bf2f(u1.y) * dv);
        u1.z = f2bf(bf2f(u1.z) * dv); u1.w = f2bf(bf2f(u1.w) * dv);
        *(ushort4*)(g1 + offb) = u0;
        *(ushort4*)(g1 + offb + 4) = u1;
    }
}

// ---- FUSED agg1 + gemm2, 32 nodes/block ----------------------------------
// Phase 1: 2 passes x 16 nodes (16 lanes/node), 2-deep gather, relu -> LDS.
// Phase 2: MFMA 32x64x64: 8 tiles of 16x16, 2 per wave.
__global__ __launch_bounds__(256) void aggmm_kernel(
    const unsigned short* __restrict__ G1, const int2* __restrict__ sedge2,
    const int* __restrict__ nodeStart, const int* __restrict__ nodeCnt,
    const float* __restrict__ dinv, const float* __restrict__ bias,
    const unsigned short* __restrict__ WT2, unsigned short* __restrict__ G2, int n)
{
    constexpr int BN = 32;               // nodes per block
    constexpr int ROWB = 128;            // 64 bf16 per row
    __shared__ char smem[(BN + 64) * ROWB];   // act (4KB) | ws (8KB)
    char* xs = smem;
    char* ws = smem + BN * ROWB;
    const int tid = threadIdx.x;
    const int nodeBase = blockIdx.x * BN;

    // stage W2^T swizzled (64 rows)
    for (int q = tid; q < 64 * 8; q += 256) {
        int r = q >> 3, s = q & 7;
        uint4 v = *(const uint4*)(WT2 + r * 64 + s * 8);
        *(uint4*)(ws + r * ROWB + ((s ^ (r & 7)) * 16)) = v;
    }

    // ---- phase 1: aggregate 32 nodes into LDS act
    int p = tid & 15;
    float4 bb = *(const float4*)&bias[p * 4];
    #pragma unroll
    for (int pass = 0; pass < 2; ++pass) {
        int r = pass * 16 + (tid >> 4);
        int node = nodeBase + r;
        float4 o = make_float4(0.f, 0.f, 0.f, 0.f);
        if (node < n) {
            ushort4 sv = *(const ushort4*)&G1[(size_t)node * 64 + p * 4];
            float4 a = make_float4(bf2f(sv.x), bf2f(sv.y), bf2f(sv.z), bf2f(sv.w));
            a = gather2(G1, sedge2 + nodeStart[node], nodeCnt[node], p, a);
            float di = dinv[node];
            o.x = fmaxf(fmaf(di, a.x, bb.x), 0.f);
            o.y = fmaxf(fmaf(di, a.y, bb.y), 0.f);
            o.z = fmaxf(fmaf(di, a.z, bb.z), 0.f);
            o.w = fmaxf(fmaf(di, a.w, bb.w), 0.f);
        }
        ushort4 h;
        h.x = f2bf(o.x); h.y = f2bf(o.y); h.z = f2bf(o.z); h.w = f2bf(o.w);
        *(ushort4*)(xs + r * ROWB + (((p >> 1) ^ (r & 7)) * 16) + (p & 1) * 8) = h;
    }
    __syncthreads();

    // ---- phase 2: MFMA (M=32, N=64, K=64); wave w: row-block w>>1, cols (w&1)*2+{0,1}
    const int lane = tid & 63;
    const int w = tid >> 6;
    const int lr = lane & 15;
    const int lk = lane >> 4;
    const int rb = w >> 1;
    const int arow = rb * 16 + lr;

    f32x4 acc[2] = {};
    #pragma unroll
    for (int kb = 0; kb < 2; ++kb) {
        int s = kb * 4 + lk;
        bf16x8 a = *(bf16x8*)(xs + arow * ROWB + ((s ^ (arow & 7)) * 16));
        #pragma unroll
        for (int cc = 0; cc < 2; ++cc) {
            int c = ((w & 1) * 2 + cc) * 16 + lr;
            bf16x8 b = *(bf16x8*)(ws + c * ROWB + ((s ^ (c & 7)) * 16));
            acc[cc] = __builtin_amdgcn_mfma_f32_16x16x32_bf16(a, b, acc[cc], 0, 0, 0);
        }
    }

    int rowbase = nodeBase + rb * 16 + (lk << 2);
    #pragma unroll
    for (int j = 0; j < 4; ++j) {
        int node = rowbase + j;
        if (node >= n) continue;
        float dv = dinv[node];
        #pragma unroll
        for (int cc = 0; cc < 2; ++cc)
            G2[(size_t)node * 64 + ((w & 1) * 2 + cc) * 16 + lr] = f2bf(acc[cc][j] * dv);
    }
}

// ---- final aggregation (f32 out), 2-deep ---------------------------------
__global__ __launch_bounds__(256) void agg_kernel(
    const unsigned short* __restrict__ G, const int2* __restrict__ sedge2,
    const int* __restrict__ nodeStart, const int* __restrict__ nodeCnt,
    const float* __restrict__ dinv, const float* __restrict__ bias,
    float* __restrict__ OUT, int n)
{
    int t = blockIdx.x * blockDim.x + threadIdx.x;
    if (t >= n * 16) return;
    int node = t >> 4, p = t & 15;

    ushort4 sv = *(const ushort4*)&G[(size_t)node * 64 + p * 4];
    float4 a = make_float4(bf2f(sv.x), bf2f(sv.y), bf2f(sv.z), bf2f(sv.w));
    a = gather2(G, sedge2 + nodeStart[node], nodeCnt[node], p, a);

    float di = dinv[node];
    float4 bb = *(const float4*)&bias[p * 4];
    float4 o;
    o.x = fmaxf(fmaf(di, a.x, bb.x), 0.f);
    o.y = fmaxf(fmaf(di, a.y, bb.y), 0.f);
    o.z = fmaxf(fmaf(di, a.z, bb.z), 0.f);
    o.w = fmaxf(fmaf(di, a.w, bb.w), 0.f);
    *(float4*)&OUT[(size_t)node * 64 + p * 4] = o;
}

extern "C" void kernel_launch(void* const* d_in, const int* in_sizes, int n_in,
                              void* d_out, int out_size, void* d_ws, size_t ws_size,
                              hipStream_t stream) {
    const float* x     = (const float*)d_in[0];
    const int*   eidx  = (const int*)d_in[1];
    const float* eattr = (const float*)d_in[2];
    const float* W1    = (const float*)d_in[3];
    const float* b1    = (const float*)d_in[4];
    const float* W2    = (const float*)d_in[5];
    const float* b2    = (const float*)d_in[6];
    float* out = (float*)d_out;

    const int n = in_sizes[0] / 128;
    const int E = in_sizes[2];
    const int* row = eidx;
    const int* col = eidx + E;

    const int NBKT = (n + BNODES - 1) / BNODES;    // 782
    const int NEB  = (E + EPB - 1) / EPB;          // 245 (<=256 required)

    int2*  sedge1 = (int2*)d_ws;
    int2*  sedge2 = sedge1 + (size_t)E;
    unsigned short* g1 = (unsigned short*)(sedge2 + (size_t)E);
    unsigned short* g2 = g1 + (size_t)n * 64;
    unsigned short* WT1 = g2 + (size_t)n * 64;
    unsigned short* WT2 = WT1 + 64 * 128;
    float* dinv      = (float*)(WT2 + 64 * 64);
    int*   nodeStart = (int*)(dinv + n);
    int*   nodeCnt   = nodeStart + n;
    int*   H         = nodeCnt + n;
    int*   rowSum    = H + (size_t)NEB * NBKT;
    int*   bktStart  = rowSum + NBKT;

    const int nbG  = (n + 63) / 64;
    const int nbG2 = (n + 31) / 32;
    const int nbA  = (int)(((size_t)n * 16 + 255) / 256);

    hist_kernel<<<NEB + 48, 256, 0, stream>>>(col, H, E, NBKT, W1, W2, WT1, WT2, NEB);
    rowscan_kernel<<<NBKT, 256, 0, stream>>>(H, rowSum, NEB, NBKT);
    bktscan_kernel<<<1, 256, 0, stream>>>(rowSum, bktStart, NBKT);
    scatter_gemm_kernel<<<NEB + nbG, 256, 0, stream>>>(
        row, col, eattr, H, bktStart, sedge1, E, NBKT, NEB, x, WT1, g1, n);
    fine_kernel<<<NBKT, 256, 0, stream>>>(sedge1, bktStart, sedge2, nodeStart,
                                          nodeCnt, dinv, g1, n);

    aggmm_kernel<<<nbG2, 256, 0, stream>>>(g1, sedge2, nodeStart, nodeCnt, dinv, b1, WT2, g2, n);
    agg_kernel<<<nbA, 256, 0, stream>>>(g2, sedge2, nodeStart, nodeCnt, dinv, b2, out, n);
}

// Round 11
// 122.915 us; speedup vs baseline: 1.0867x; 1.0282x over previous
//
#include <hip/hip_runtime.h>

// GCN restructure:  deg[c] = 1 + sum_{col=c} w;  dinv = rsqrt(deg)
//   g = (X@W) * dinv[node]        (MFMA bf16; dinv applied late)
//   out[c] = relu( dinv[c] * ( g[c] + sum_{e: col=c} w_e * g[row_e] ) + b )
//
// R11: coarse buckets widened to 512 nodes (NBKT=196) and the coarse scatter
// now counting-sorts its 4096 edges in LDS before draining, so global writes
// are sequential runs of ~168B instead of scattered 8B (R10 measured 3x HBM
// write amplification on sedge1: 8MB payload -> ~24MB writeback, runs from
// different XCDs sharing sectors).  fine_kernel moves to 512 threads/block.
// Session facts: global atomic ~62B memory-side; 64M LDS atomics = 445us;
// agg kernels latency-bound on 2-level gather, occupancy is the lever.

#define BNODES 512
#define LB 9                 // log2(BNODES)
#define MAXBKT 256           // supports n <= 131072
#define EPT 16
#define EPB (256 * EPT)      // 4096 edges per sort block; NEB<=256 for E<=1M

typedef __attribute__((ext_vector_type(8))) short bf16x8;
typedef __attribute__((ext_vector_type(4))) float f32x4;

__device__ __forceinline__ unsigned short f2bf(float f) {
    unsigned u = __float_as_uint(f);
    u = (u + 0x7FFF + ((u >> 16) & 1)) >> 16;   // rtne
    return (unsigned short)u;
}
__device__ __forceinline__ float bf2f(unsigned short h) {
    return __uint_as_float(((unsigned)h) << 16);
}

__device__ __forceinline__ int waveIncScan(int v, int lane) {
    #pragma unroll
    for (int d = 1; d < 64; d <<= 1) {
        int u = __shfl_up(v, d, 64);
        if (lane >= d) v += u;
    }
    return v;
}

// inclusive scan across NW*64 threads
template<int NW>
__device__ __forceinline__ int blockIncScan(int v, int t, int* wt) {
    int lane = t & 63, w = t >> 6;
    int s = waveIncScan(v, lane);
    if (lane == 63) wt[w] = s;
    __syncthreads();
    int add = 0;
    #pragma unroll
    for (int i = 0; i < NW - 1; ++i) if (i < w) add += wt[i];
    return s + add;
}

// 2-deep gather accumulate (16 lanes/node, feature slice p) — proven in R8.
__device__ __forceinline__ float4 gather2(
    const unsigned short* __restrict__ G, const int2* __restrict__ eb,
    int m, int p, float4 a0)
{
    float4 a1 = make_float4(0.f, 0.f, 0.f, 0.f);
    int j = 0;
    for (; j + 1 < m; j += 2) {
        int2 pk0 = eb[j];
        int2 pk1 = eb[j + 1];
        float w0 = __int_as_float(pk0.y);
        float w1 = __int_as_float(pk1.y);
        ushort4 g0 = *(const ushort4*)&G[(size_t)pk0.x * 64 + p * 4];
        ushort4 g1 = *(const ushort4*)&G[(size_t)pk1.x * 64 + p * 4];
        a0.x = fmaf(w0, bf2f(g0.x), a0.x); a0.y = fmaf(w0, bf2f(g0.y), a0.y);
        a0.z = fmaf(w0, bf2f(g0.z), a0.z); a0.w = fmaf(w0, bf2f(g0.w), a0.w);
        a1.x = fmaf(w1, bf2f(g1.x), a1.x); a1.y = fmaf(w1, bf2f(g1.y), a1.y);
        a1.z = fmaf(w1, bf2f(g1.z), a1.z); a1.w = fmaf(w1, bf2f(g1.w), a1.w);
    }
    if (j < m) {
        int2 pk = eb[j];
        float w = __int_as_float(pk.y);
        ushort4 g = *(const ushort4*)&G[(size_t)pk.x * 64 + p * 4];
        a0.x = fmaf(w, bf2f(g.x), a0.x); a0.y = fmaf(w, bf2f(g.y), a0.y);
        a0.z = fmaf(w, bf2f(g.z), a0.z); a0.w = fmaf(w, bf2f(g.w), a0.w);
    }
    a0.x += a1.x; a0.y += a1.y; a0.z += a1.z; a0.w += a1.w;
    return a0;
}

// ---- hist (+ weight transpose in tail blocks) ----------------------------

__global__ __launch_bounds__(256) void hist_kernel(
    const int* __restrict__ col, int* __restrict__ H, int E, int NBKT,
    const float* __restrict__ W1, const float* __restrict__ W2,
    unsigned short* __restrict__ WT1, unsigned short* __restrict__ WT2, int NEB)
{
    int t = threadIdx.x, blk = blockIdx.x;
    if (blk >= NEB) {
        int i = (blk - NEB) * 256 + t;
        if (i < 64 * 128) {
            int c = i >> 7, k = i & 127;
            WT1[i] = f2bf(W1[k * 64 + c]);
        } else if (i < 64 * 128 + 64 * 64) {
            int j = i - 64 * 128;
            int c = j >> 6, k = j & 63;
            WT2[j] = f2bf(W2[k * 64 + c]);
        }
        return;
    }
    __shared__ int h[MAXBKT];
    for (int b = t; b < NBKT; b += 256) h[b] = 0;
    __syncthreads();
    int base = blk * EPB;
    #pragma unroll
    for (int i = 0; i < EPT; ++i) {
        int e = base + i * 256 + t;
        if (e < E) atomicAdd(&h[col[e] >> LB], 1);
    }
    __syncthreads();
    for (int b = t; b < NBKT; b += 256) H[blk * NBKT + b] = h[b];
}

// per-bucket exclusive scan over block counts (NEB <= 256)
__global__ __launch_bounds__(256) void rowscan_kernel(
    int* __restrict__ H, int* __restrict__ rowSum, int NEB, int NBKT)
{
    __shared__ int wt[4];
    int b = blockIdx.x, t = threadIdx.x;
    int v = (t < NEB) ? H[t * NBKT + b] : 0;
    int incl = blockIncScan<4>(v, t, wt);
    if (t < NEB) H[t * NBKT + b] = incl - v;
    if (t == 255) rowSum[b] = incl;
}

// exclusive scan of bucket totals (NBKT <= 256), one block
__global__ __launch_bounds__(256) void bktscan_kernel(
    const int* __restrict__ rowSum, int* __restrict__ bktStart, int NBKT)
{
    __shared__ int wt[4];
    int t = threadIdx.x;
    int v = (t < NBKT) ? rowSum[t] : 0;
    int incl = blockIncScan<4>(v, t, wt);
    if (t < NBKT) bktStart[t] = incl - v;
    if (t == NBKT - 1) bktStart[NBKT] = incl;
}

// ---- merged (LDS-sorted scatter) + (layer-1 MFMA GEMM, unscaled) ---------
// scatter blocks: counting-sort 4096 edges in LDS, drain coalesced runs.
// gemm blocks: g1U[node,:] = bf16( X[node,:] @ W1 )  (64x64 tile).
#define SMEMSZ (EPB * 8 + EPB + MAXBKT * 16 + 32)
__global__ __launch_bounds__(256) void scatter_gemm_kernel(
    const int* __restrict__ row, const int* __restrict__ col,
    const float* __restrict__ w, const int* __restrict__ H,
    const int* __restrict__ bktStart, int2* __restrict__ sedge1,
    int E, int NBKT, int NEB,
    const float* __restrict__ X, const unsigned short* __restrict__ WT,
    unsigned short* __restrict__ G, int n)
{
    __shared__ __align__(16) char smem[SMEMSZ];
    const int t = threadIdx.x;
    const int blk = blockIdx.x;

    if (blk < NEB) {
        // ---------------- scatter role: LDS counting sort ----------------
        int2* stage = (int2*)smem;                               // 32 KB
        unsigned char* bstage = (unsigned char*)(stage + EPB);   // 4 KB
        int* lcnt  = (int*)(bstage + EPB);
        int* loff  = lcnt + MAXBKT;
        int* lcur  = loff + MAXBKT;
        int* gbase = lcur + MAXBKT;
        int* wt    = gbase + MAXBKT;

        for (int b = t; b < NBKT; b += 256) lcnt[b] = 0;
        __syncthreads();
        int base = blk * EPB;
        #pragma unroll
        for (int i = 0; i < EPT; ++i) {
            int e = base + i * 256 + t;
            if (e < E) atomicAdd(&lcnt[col[e] >> LB], 1);
        }
        __syncthreads();
        int v = (t < NBKT) ? lcnt[t] : 0;
        int incl = blockIncScan<4>(v, t, wt);
        if (t < NBKT) {
            int x0 = incl - v;
            loff[t] = x0;
            lcur[t] = x0;
            gbase[t] = bktStart[t] + H[blk * NBKT + t];
        }
        __syncthreads();
        #pragma unroll
        for (int i = 0; i < EPT; ++i) {
            int e = base + i * 256 + t;
            if (e < E) {
                int c = col[e];
                int b = c >> LB;
                int pos = atomicAdd(&lcur[b], 1);    // LDS atomic
                int2 pk;
                pk.x = row[e] | ((c & (BNODES - 1)) << 20);
                pk.y = __float_as_int(w[e]);
                stage[pos] = pk;
                bstage[pos] = (unsigned char)b;
            }
        }
        __syncthreads();
        int ecnt = E - base; if (ecnt > EPB) ecnt = EPB;
        for (int i = t; i < ecnt; i += 256) {
            int b = bstage[i];
            int g = gbase[b] + (i - loff[b]);
            sedge1[g] = stage[i];
        }
        return;
    }

    // ---------------- gemm role (K=128, f32 in, unscaled out) ----------------
    constexpr int K = 128, ROWB = 256, SLOTS = 16, CPR = 32;
    char* xs = smem;
    char* ws = smem + 64 * ROWB;
    const int nodeBase = (blk - NEB) * 64;

    for (int q = t; q < 64 * SLOTS; q += 256) {
        int r = q / SLOTS, s = q % SLOTS;
        uint4 v = *(const uint4*)(WT + r * K + s * 8);
        *(uint4*)(ws + r * ROWB + ((s ^ (r & 7)) * 16)) = v;
    }
    for (int q = t; q < 64 * CPR; q += 256) {
        int r = q / CPR, c = q % CPR;
        int node = nodeBase + r;
        float4 v = make_float4(0.f, 0.f, 0.f, 0.f);
        if (node < n) v = *(const float4*)(X + (size_t)node * K + c * 4);
        ushort4 h;
        h.x = f2bf(v.x); h.y = f2bf(v.y); h.z = f2bf(v.z); h.w = f2bf(v.w);
        *(ushort4*)(xs + r * ROWB + (((c >> 1) ^ (r & 7)) * 16) + (c & 1) * 8) = h;
    }
    __syncthreads();

    const int lane = t & 63;
    const int wv = t >> 6;
    const int lr = lane & 15;
    const int lk = lane >> 4;
    const int arow = (wv << 4) + lr;

    f32x4 acc[4] = {};
    #pragma unroll
    for (int kb = 0; kb < 4; ++kb) {
        int s = kb * 4 + lk;
        bf16x8 a = *(bf16x8*)(xs + arow * ROWB + ((s ^ (arow & 7)) * 16));
        #pragma unroll
        for (int cb = 0; cb < 4; ++cb) {
            int c = cb * 16 + lr;
            bf16x8 b = *(bf16x8*)(ws + c * ROWB + ((s ^ (c & 7)) * 16));
            acc[cb] = __builtin_amdgcn_mfma_f32_16x16x32_bf16(a, b, acc[cb], 0, 0, 0);
        }
    }

    int rowbase = nodeBase + (wv << 4) + (lk << 2);
    #pragma unroll
    for (int j = 0; j < 4; ++j) {
        int node = rowbase + j;
        if (node >= n) continue;
        #pragma unroll
        for (int cb = 0; cb < 4; ++cb)
            G[(size_t)node * 64 + cb * 16 + lr] = f2bf(acc[cb][j]);
    }
}

// ---- fine: 512-node bucket -> per-node CSR + dinv + scale own g1 rows ----
__global__ __launch_bounds__(512) void fine_kernel(
    const int2* __restrict__ sedge1, const int* __restrict__ bktStart,
    int2* __restrict__ sedge2, int* __restrict__ nodeStart,
    int* __restrict__ nodeCnt, float* __restrict__ dinv,
    unsigned short* __restrict__ g1, int n)
{
    __shared__ int cnt[BNODES];
    __shared__ float wsum[BNODES];
    __shared__ int off[BNODES];
    __shared__ int cur[BNODES];
    __shared__ float dloc[BNODES];
    __shared__ int wt[8];
    int b = blockIdx.x, t = threadIdx.x;
    cnt[t] = 0; wsum[t] = 1.0f;          // t in [0,512) == BNODES
    __syncthreads();
    int s = bktStart[b], e = bktStart[b + 1];
    for (int j = s + t; j < e; j += 512) {
        int2 pk = sedge1[j];
        int ld = pk.x >> 20;
        atomicAdd(&cnt[ld], 1);
        atomicAdd(&wsum[ld], __int_as_float(pk.y));
    }
    __syncthreads();
    int v = cnt[t];
    int incl = blockIncScan<8>(v, t, wt);          // has __syncthreads
    int x0 = s + incl - v;
    off[t] = x0;
    cur[t] = x0;
    dloc[t] = rsqrtf(wsum[t]);
    __syncthreads();
    int node = b * BNODES + t;
    if (node < n) {
        nodeStart[node] = off[t];
        nodeCnt[node] = cnt[t];
        dinv[node] = dloc[t];
    }
    for (int j = s + t; j < e; j += 512) {
        int2 pk = sedge1[j];
        int ld = pk.x >> 20;
        int pos = atomicAdd(&cur[ld], 1);          // LDS atomic
        sedge2[pos] = make_int2(pk.x & 0xFFFFF, pk.y);
    }
    // scale own bucket's g1 rows by dinv (g1 was written unscaled)
    for (int q = t; q < BNODES * 8; q += 512) {
        int r = q >> 3, cc = q & 7;
        int nd = b * BNODES + r;
        if (nd >= n) continue;
        float dv = dloc[r];
        size_t offb = (size_t)nd * 64 + cc * 8;
        ushort4 u0 = *(const ushort4*)(g1 + offb);
        ushort4 u1 = *(const ushort4*)(g1 + offb + 4);
        u0.x = f2bf(bf2f(u0.x) * dv); u0.y = f2bf(bf2f(u0.y) * dv);
        u0.z = f2bf(bf2f(u0.z) * dv); u0.w = f2bf(bf2f(u0.w) * dv);
        u1.x = f2bf(bf2f(u1.x) * dv); u1.y = f2bf(bf2f(u1.y) * dv);
        u1.z = f2bf(bf2f(u1.z) * dv); u1.w = f2bf(bf2f(u1.w) * dv);
        *(ushort4*)(g1 + offb) = u0;
        *(ushort4*)(g1 + offb + 4) = u1;
    }
}

// ---- FUSED agg1 + gemm2, 32 nodes/block ----------------------------------
__global__ __launch_bounds__(256) void aggmm_kernel(
    const unsigned short* __restrict__ G1, const int2* __restrict__ sedge2,
    const int* __restrict__ nodeStart, const int* __restrict__ nodeCnt,
    const float* __restrict__ dinv, const float* __restrict__ bias,
    const unsigned short* __restrict__ WT2, unsigned short* __restrict__ G2, int n)
{
    constexpr int BN = 32;
    constexpr int ROWB = 128;
    __shared__ char smem[(BN + 64) * ROWB];   // act (4KB) | ws (8KB)
    char* xs = smem;
    char* ws = smem + BN * ROWB;
    const int tid = threadIdx.x;
    const int nodeBase = blockIdx.x * BN;

    for (int q = tid; q < 64 * 8; q += 256) {
        int r = q >> 3, s = q & 7;
        uint4 v = *(const uint4*)(WT2 + r * 64 + s * 8);
        *(uint4*)(ws + r * ROWB + ((s ^ (r & 7)) * 16)) = v;
    }

    int p = tid & 15;
    float4 bb = *(const float4*)&bias[p * 4];
    #pragma unroll
    for (int pass = 0; pass < 2; ++pass) {
        int r = pass * 16 + (tid >> 4);
        int node = nodeBase + r;
        float4 o = make_float4(0.f, 0.f, 0.f, 0.f);
        if (node < n) {
            ushort4 sv = *(const ushort4*)&G1[(size_t)node * 64 + p * 4];
            float4 a = make_float4(bf2f(sv.x), bf2f(sv.y), bf2f(sv.z), bf2f(sv.w));
            a = gather2(G1, sedge2 + nodeStart[node], nodeCnt[node], p, a);
            float di = dinv[node];
            o.x = fmaxf(fmaf(di, a.x, bb.x), 0.f);
            o.y = fmaxf(fmaf(di, a.y, bb.y), 0.f);
            o.z = fmaxf(fmaf(di, a.z, bb.z), 0.f);
            o.w = fmaxf(fmaf(di, a.w, bb.w), 0.f);
        }
        ushort4 h;
        h.x = f2bf(o.x); h.y = f2bf(o.y); h.z = f2bf(o.z); h.w = f2bf(o.w);
        *(ushort4*)(xs + r * ROWB + (((p >> 1) ^ (r & 7)) * 16) + (p & 1) * 8) = h;
    }
    __syncthreads();

    const int lane = tid & 63;
    const int w = tid >> 6;
    const int lr = lane & 15;
    const int lk = lane >> 4;
    const int rb = w >> 1;
    const int arow = rb * 16 + lr;

    f32x4 acc[2] = {};
    #pragma unroll
    for (int kb = 0; kb < 2; ++kb) {
        int s = kb * 4 + lk;
        bf16x8 a = *(bf16x8*)(xs + arow * ROWB + ((s ^ (arow & 7)) * 16));
        #pragma unroll
        for (int cc = 0; cc < 2; ++cc) {
            int c = ((w & 1) * 2 + cc) * 16 + lr;
            bf16x8 b = *(bf16x8*)(ws + c * ROWB + ((s ^ (c & 7)) * 16));
            acc[cc] = __builtin_amdgcn_mfma_f32_16x16x32_bf16(a, b, acc[cc], 0, 0, 0);
        }
    }

    int rowbase = nodeBase + rb * 16 + (lk << 2);
    #pragma unroll
    for (int j = 0; j < 4; ++j) {
        int node = rowbase + j;
        if (node >= n) continue;
        float dv = dinv[node];
        #pragma unroll
        for (int cc = 0; cc < 2; ++cc)
            G2[(size_t)node * 64 + ((w & 1) * 2 + cc) * 16 + lr] = f2bf(acc[cc][j] * dv);
    }
}

// ---- final aggregation (f32 out) -----------------------------------------
__global__ __launch_bounds__(256) void agg_kernel(
    const unsigned short* __restrict__ G, const int2* __restrict__ sedge2,
    const int* __restrict__ nodeStart, const int* __restrict__ nodeCnt,
    const float* __restrict__ dinv, const float* __restrict__ bias,
    float* __restrict__ OUT, int n)
{
    int t = blockIdx.x * blockDim.x + threadIdx.x;
    if (t >= n * 16) return;
    int node = t >> 4, p = t & 15;

    ushort4 sv = *(const ushort4*)&G[(size_t)node * 64 + p * 4];
    float4 a = make_float4(bf2f(sv.x), bf2f(sv.y), bf2f(sv.z), bf2f(sv.w));
    a = gather2(G, sedge2 + nodeStart[node], nodeCnt[node], p, a);

    float di = dinv[node];
    float4 bb = *(const float4*)&bias[p * 4];
    float4 o;
    o.x = fmaxf(fmaf(di, a.x, bb.x), 0.f);
    o.y = fmaxf(fmaf(di, a.y, bb.y), 0.f);
    o.z = fmaxf(fmaf(di, a.z, bb.z), 0.f);
    o.w = fmaxf(fmaf(di, a.w, bb.w), 0.f);
    *(float4*)&OUT[(size_t)node * 64 + p * 4] = o;
}

extern "C" void kernel_launch(void* const* d_in, const int* in_sizes, int n_in,
                              void* d_out, int out_size, void* d_ws, size_t ws_size,
                              hipStream_t stream) {
    const float* x     = (const float*)d_in[0];
    const int*   eidx  = (const int*)d_in[1];
    const float* eattr = (const float*)d_in[2];
    const float* W1    = (const float*)d_in[3];
    const float* b1    = (const float*)d_in[4];
    const float* W2    = (const float*)d_in[5];
    const float* b2    = (const float*)d_in[6];
    float* out = (float*)d_out;

    const int n = in_sizes[0] / 128;
    const int E = in_sizes[2];
    const int* row = eidx;
    const int* col = eidx + E;

    const int NBKT = (n + BNODES - 1) / BNODES;    // 196
    const int NEB  = (E + EPB - 1) / EPB;          // 245 (<=256 required)

    int2*  sedge1 = (int2*)d_ws;
    int2*  sedge2 = sedge1 + (size_t)E;
    unsigned short* g1 = (unsigned short*)(sedge2 + (size_t)E);
    unsigned short* g2 = g1 + (size_t)n * 64;
    unsigned short* WT1 = g2 + (size_t)n * 64;
    unsigned short* WT2 = WT1 + 64 * 128;
    float* dinv      = (float*)(WT2 + 64 * 64);
    int*   nodeStart = (int*)(dinv + n);
    int*   nodeCnt   = nodeStart + n;
    int*   H         = nodeCnt + n;
    int*   rowSum    = H + (size_t)NEB * NBKT;
    int*   bktStart  = rowSum + NBKT;

    const int nbG  = (n + 63) / 64;
    const int nbG2 = (n + 31) / 32;
    const int nbA  = (int)(((size_t)n * 16 + 255) / 256);

    hist_kernel<<<NEB + 48, 256, 0, stream>>>(col, H, E, NBKT, W1, W2, WT1, WT2, NEB);
    rowscan_kernel<<<NBKT, 256, 0, stream>>>(H, rowSum, NEB, NBKT);
    bktscan_kernel<<<1, 256, 0, stream>>>(rowSum, bktStart, NBKT);
    scatter_gemm_kernel<<<NEB + nbG, 256, 0, stream>>>(
        row, col, eattr, H, bktStart, sedge1, E, NBKT, NEB, x, WT1, g1, n);
    fine_kernel<<<NBKT, 512, 0, stream>>>(sedge1, bktStart, sedge2, nodeStart,
                                          nodeCnt, dinv, g1, n);

    aggmm_kernel<<<nbG2, 256, 0, stream>>>(g1, sedge2, nodeStart, nodeCnt, dinv, b1, WT2, g2, n);
    agg_kernel<<<nbA, 256, 0, stream>>>(g2, sedge2, nodeStart, nodeCnt, dinv, b2, out, n);
}

// Round 12
// 112.467 us; speedup vs baseline: 1.1877x; 1.0929x over previous
//
#include <hip/hip_runtime.h>

// GCN restructure:  deg[c] = 1 + sum_{col=c} w;  dinv = rsqrt(deg)
//   g = (X@W) * dinv[node]        (MFMA bf16; dinv applied late)
//   out[c] = relu( dinv[c] * ( g[c] + sum_{e: col=c} w_e * g[row_e] ) + b )
//
// R12: gather loops rebuilt for issue efficiency: 8 lanes/node x ushort8
// (16B/lane, half the memory instructions, 8 nodes/wave in flight) and
// descriptor PAIRS loaded as one int4 (halves dependent descriptor hops).
// aggmm phase-1 is now a single 32-node pass whose bf16x8 output slice maps
// 1:1 onto a 16B swizzled LDS slot of the MFMA A-tile.
// Session facts: global atomic ~62B memory-side; 64M LDS atomics = 445us;
// aggs latency-bound (R9: 56MB FETCH at 15-19% peak); R10: aggmm was
// grid-limited at 34% occupancy -> 32-node blocks; R11: LDS-sorted scatter.

#define BNODES 512
#define LB 9
#define MAXBKT 256
#define EPT 16
#define EPB (256 * EPT)

typedef __attribute__((ext_vector_type(8))) short bf16x8;
typedef __attribute__((ext_vector_type(8))) unsigned short u16x8;
typedef __attribute__((ext_vector_type(8))) float f32x8;
typedef __attribute__((ext_vector_type(4))) float f32x4;

__device__ __forceinline__ unsigned short f2bf(float f) {
    unsigned u = __float_as_uint(f);
    u = (u + 0x7FFF + ((u >> 16) & 1)) >> 16;   // rtne
    return (unsigned short)u;
}
__device__ __forceinline__ float bf2f(unsigned short h) {
    return __uint_as_float(((unsigned)h) << 16);
}
__device__ __forceinline__ f32x8 bf8tof(u16x8 u) {
    f32x8 r;
    #pragma unroll
    for (int i = 0; i < 8; ++i) r[i] = bf2f(u[i]);
    return r;
}

__device__ __forceinline__ int waveIncScan(int v, int lane) {
    #pragma unroll
    for (int d = 1; d < 64; d <<= 1) {
        int u = __shfl_up(v, d, 64);
        if (lane >= d) v += u;
    }
    return v;
}

template<int NW>
__device__ __forceinline__ int blockIncScan(int v, int t, int* wt) {
    int lane = t & 63, w = t >> 6;
    int s = waveIncScan(v, lane);
    if (lane == 63) wt[w] = s;
    __syncthreads();
    int add = 0;
    #pragma unroll
    for (int i = 0; i < NW - 1; ++i) if (i < w) add += wt[i];
    return s + add;
}

// 8-lane/node gather: descriptor pairs via int4, rows via ushort8 (16B/lane).
__device__ __forceinline__ f32x8 gather8(
    const unsigned short* __restrict__ G, const int2* __restrict__ sedge,
    int s, int m, int p8, f32x8 a0)
{
    f32x8 a1 = (f32x8)0.f;
    int e = s, e_end = s + m;
    // peel to 16B-aligned pair boundary
    if ((((unsigned long long)(sedge + e)) & 8) && e < e_end) {
        int2 pk = sedge[e++];
        float w = __int_as_float(pk.y);
        a0 += w * bf8tof(*(const u16x8*)&G[(size_t)pk.x * 64 + p8 * 8]);
    }
    for (; e + 1 < e_end; e += 2) {
        int4 pp = *(const int4*)&sedge[e];
        float w0 = __int_as_float(pp.y);
        float w1 = __int_as_float(pp.w);
        u16x8 g0 = *(const u16x8*)&G[(size_t)pp.x * 64 + p8 * 8];
        u16x8 g1 = *(const u16x8*)&G[(size_t)pp.z * 64 + p8 * 8];
        a0 += w0 * bf8tof(g0);
        a1 += w1 * bf8tof(g1);
    }
    if (e < e_end) {
        int2 pk = sedge[e];
        float w = __int_as_float(pk.y);
        a0 += w * bf8tof(*(const u16x8*)&G[(size_t)pk.x * 64 + p8 * 8]);
    }
    return a0 + a1;
}

// ---- hist (+ weight transpose in tail blocks) ----------------------------

__global__ __launch_bounds__(256) void hist_kernel(
    const int* __restrict__ col, int* __restrict__ H, int E, int NBKT,
    const float* __restrict__ W1, const float* __restrict__ W2,
    unsigned short* __restrict__ WT1, unsigned short* __restrict__ WT2, int NEB)
{
    int t = threadIdx.x, blk = blockIdx.x;
    if (blk >= NEB) {
        int i = (blk - NEB) * 256 + t;
        if (i < 64 * 128) {
            int c = i >> 7, k = i & 127;
            WT1[i] = f2bf(W1[k * 64 + c]);
        } else if (i < 64 * 128 + 64 * 64) {
            int j = i - 64 * 128;
            int c = j >> 6, k = j & 63;
            WT2[j] = f2bf(W2[k * 64 + c]);
        }
        return;
    }
    __shared__ int h[MAXBKT];
    for (int b = t; b < NBKT; b += 256) h[b] = 0;
    __syncthreads();
    int base = blk * EPB;
    #pragma unroll
    for (int i = 0; i < EPT; ++i) {
        int e = base + i * 256 + t;
        if (e < E) atomicAdd(&h[col[e] >> LB], 1);
    }
    __syncthreads();
    for (int b = t; b < NBKT; b += 256) H[blk * NBKT + b] = h[b];
}

__global__ __launch_bounds__(256) void rowscan_kernel(
    int* __restrict__ H, int* __restrict__ rowSum, int NEB, int NBKT)
{
    __shared__ int wt[4];
    int b = blockIdx.x, t = threadIdx.x;
    int v = (t < NEB) ? H[t * NBKT + b] : 0;
    int incl = blockIncScan<4>(v, t, wt);
    if (t < NEB) H[t * NBKT + b] = incl - v;
    if (t == 255) rowSum[b] = incl;
}

__global__ __launch_bounds__(256) void bktscan_kernel(
    const int* __restrict__ rowSum, int* __restrict__ bktStart, int NBKT)
{
    __shared__ int wt[4];
    int t = threadIdx.x;
    int v = (t < NBKT) ? rowSum[t] : 0;
    int incl = blockIncScan<4>(v, t, wt);
    if (t < NBKT) bktStart[t] = incl - v;
    if (t == NBKT - 1) bktStart[NBKT] = incl;
}

// ---- merged (LDS-sorted scatter) + (layer-1 MFMA GEMM, unscaled) ---------
#define SMEMSZ (EPB * 8 + EPB + MAXBKT * 16 + 32)
__global__ __launch_bounds__(256) void scatter_gemm_kernel(
    const int* __restrict__ row, const int* __restrict__ col,
    const float* __restrict__ w, const int* __restrict__ H,
    const int* __restrict__ bktStart, int2* __restrict__ sedge1,
    int E, int NBKT, int NEB,
    const float* __restrict__ X, const unsigned short* __restrict__ WT,
    unsigned short* __restrict__ G, int n)
{
    __shared__ __align__(16) char smem[SMEMSZ];
    const int t = threadIdx.x;
    const int blk = blockIdx.x;

    if (blk < NEB) {
        int2* stage = (int2*)smem;
        unsigned char* bstage = (unsigned char*)(stage + EPB);
        int* lcnt  = (int*)(bstage + EPB);
        int* loff  = lcnt + MAXBKT;
        int* lcur  = loff + MAXBKT;
        int* gbase = lcur + MAXBKT;
        int* wt    = gbase + MAXBKT;

        for (int b = t; b < NBKT; b += 256) lcnt[b] = 0;
        __syncthreads();
        int base = blk * EPB;
        #pragma unroll
        for (int i = 0; i < EPT; ++i) {
            int e = base + i * 256 + t;
            if (e < E) atomicAdd(&lcnt[col[e] >> LB], 1);
        }
        __syncthreads();
        int v = (t < NBKT) ? lcnt[t] : 0;
        int incl = blockIncScan<4>(v, t, wt);
        if (t < NBKT) {
            int x0 = incl - v;
            loff[t] = x0;
            lcur[t] = x0;
            gbase[t] = bktStart[t] + H[blk * NBKT + t];
        }
        __syncthreads();
        #pragma unroll
        for (int i = 0; i < EPT; ++i) {
            int e = base + i * 256 + t;
            if (e < E) {
                int c = col[e];
                int b = c >> LB;
                int pos = atomicAdd(&lcur[b], 1);    // LDS atomic
                int2 pk;
                pk.x = row[e] | ((c & (BNODES - 1)) << 20);
                pk.y = __float_as_int(w[e]);
                stage[pos] = pk;
                bstage[pos] = (unsigned char)b;
            }
        }
        __syncthreads();
        int ecnt = E - base; if (ecnt > EPB) ecnt = EPB;
        for (int i = t; i < ecnt; i += 256) {
            int b = bstage[i];
            int g = gbase[b] + (i - loff[b]);
            sedge1[g] = stage[i];
        }
        return;
    }

    constexpr int K = 128, ROWB = 256, SLOTS = 16, CPR = 32;
    char* xs = smem;
    char* ws = smem + 64 * ROWB;
    const int nodeBase = (blk - NEB) * 64;

    for (int q = t; q < 64 * SLOTS; q += 256) {
        int r = q / SLOTS, s = q % SLOTS;
        uint4 v = *(const uint4*)(WT + r * K + s * 8);
        *(uint4*)(ws + r * ROWB + ((s ^ (r & 7)) * 16)) = v;
    }
    for (int q = t; q < 64 * CPR; q += 256) {
        int r = q / CPR, c = q % CPR;
        int node = nodeBase + r;
        float4 v = make_float4(0.f, 0.f, 0.f, 0.f);
        if (node < n) v = *(const float4*)(X + (size_t)node * K + c * 4);
        ushort4 h;
        h.x = f2bf(v.x); h.y = f2bf(v.y); h.z = f2bf(v.z); h.w = f2bf(v.w);
        *(ushort4*)(xs + r * ROWB + (((c >> 1) ^ (r & 7)) * 16) + (c & 1) * 8) = h;
    }
    __syncthreads();

    const int lane = t & 63;
    const int wv = t >> 6;
    const int lr = lane & 15;
    const int lk = lane >> 4;
    const int arow = (wv << 4) + lr;

    f32x4 acc[4] = {};
    #pragma unroll
    for (int kb = 0; kb < 4; ++kb) {
        int s = kb * 4 + lk;
        bf16x8 a = *(bf16x8*)(xs + arow * ROWB + ((s ^ (arow & 7)) * 16));
        #pragma unroll
        for (int cb = 0; cb < 4; ++cb) {
            int c = cb * 16 + lr;
            bf16x8 b = *(bf16x8*)(ws + c * ROWB + ((s ^ (c & 7)) * 16));
            acc[cb] = __builtin_amdgcn_mfma_f32_16x16x32_bf16(a, b, acc[cb], 0, 0, 0);
        }
    }

    int rowbase = nodeBase + (wv << 4) + (lk << 2);
    #pragma unroll
    for (int j = 0; j < 4; ++j) {
        int node = rowbase + j;
        if (node >= n) continue;
        #pragma unroll
        for (int cb = 0; cb < 4; ++cb)
            G[(size_t)node * 64 + cb * 16 + lr] = f2bf(acc[cb][j]);
    }
}

// ---- fine: 512-node bucket -> per-node CSR + dinv + scale own g1 rows ----
__global__ __launch_bounds__(512) void fine_kernel(
    const int2* __restrict__ sedge1, const int* __restrict__ bktStart,
    int2* __restrict__ sedge2, int* __restrict__ nodeStart,
    int* __restrict__ nodeCnt, float* __restrict__ dinv,
    unsigned short* __restrict__ g1, int n)
{
    __shared__ int cnt[BNODES];
    __shared__ float wsum[BNODES];
    __shared__ int off[BNODES];
    __shared__ int cur[BNODES];
    __shared__ float dloc[BNODES];
    __shared__ int wt[8];
    int b = blockIdx.x, t = threadIdx.x;
    cnt[t] = 0; wsum[t] = 1.0f;
    __syncthreads();
    int s = bktStart[b], e = bktStart[b + 1];
    for (int j = s + t; j < e; j += 512) {
        int2 pk = sedge1[j];
        int ld = pk.x >> 20;
        atomicAdd(&cnt[ld], 1);
        atomicAdd(&wsum[ld], __int_as_float(pk.y));
    }
    __syncthreads();
    int v = cnt[t];
    int incl = blockIncScan<8>(v, t, wt);
    int x0 = s + incl - v;
    off[t] = x0;
    cur[t] = x0;
    dloc[t] = rsqrtf(wsum[t]);
    __syncthreads();
    int node = b * BNODES + t;
    if (node < n) {
        nodeStart[node] = off[t];
        nodeCnt[node] = cnt[t];
        dinv[node] = dloc[t];
    }
    for (int j = s + t; j < e; j += 512) {
        int2 pk = sedge1[j];
        int ld = pk.x >> 20;
        int pos = atomicAdd(&cur[ld], 1);
        sedge2[pos] = make_int2(pk.x & 0xFFFFF, pk.y);
    }
    for (int q = t; q < BNODES * 8; q += 512) {
        int r = q >> 3, cc = q & 7;
        int nd = b * BNODES + r;
        if (nd >= n) continue;
        float dv = dloc[r];
        size_t offb = (size_t)nd * 64 + cc * 8;
        ushort4 u0 = *(const ushort4*)(g1 + offb);
        ushort4 u1 = *(const ushort4*)(g1 + offb + 4);
        u0.x = f2bf(bf2f(u0.x) * dv); u0.y = f2bf(bf2f(u0.y) * dv);
        u0.z = f2bf(bf2f(u0.z) * dv); u0.w = f2bf(bf2f(u0.w) * dv);
        u1.x = f2bf(bf2f(u1.x) * dv); u1.y = f2bf(bf2f(u1.y) * dv);
        u1.z = f2bf(bf2f(u1.z) * dv); u1.w = f2bf(bf2f(u1.w) * dv);
        *(ushort4*)(g1 + offb) = u0;
        *(ushort4*)(g1 + offb + 4) = u1;
    }
}

// ---- FUSED agg1 + gemm2, 32 nodes/block, single-pass 8-lane agg ----------
__global__ __launch_bounds__(256) void aggmm_kernel(
    const unsigned short* __restrict__ G1, const int2* __restrict__ sedge2,
    const int* __restrict__ nodeStart, const int* __restrict__ nodeCnt,
    const float* __restrict__ dinv, const float* __restrict__ bias,
    const unsigned short* __restrict__ WT2, unsigned short* __restrict__ G2, int n)
{
    constexpr int BN = 32;
    constexpr int ROWB = 128;
    __shared__ char smem[(BN + 64) * ROWB];   // act (4KB) | ws (8KB)
    char* xs = smem;
    char* ws = smem + BN * ROWB;
    const int tid = threadIdx.x;
    const int nodeBase = blockIdx.x * BN;

    for (int q = tid; q < 64 * 8; q += 256) {
        int r = q >> 3, s = q & 7;
        uint4 v = *(const uint4*)(WT2 + r * 64 + s * 8);
        *(uint4*)(ws + r * ROWB + ((s ^ (r & 7)) * 16)) = v;
    }

    // ---- phase 1: single pass, 32 nodes x 8 slices
    int p8 = tid & 7;
    int r = tid >> 3;
    int node = nodeBase + r;
    f32x8 o = (f32x8)0.f;
    if (node < n) {
        f32x8 a = bf8tof(*(const u16x8*)&G1[(size_t)node * 64 + p8 * 8]);
        a = gather8(G1, sedge2, nodeStart[node], nodeCnt[node], p8, a);
        float di = dinv[node];
        #pragma unroll
        for (int i = 0; i < 8; ++i)
            o[i] = fmaxf(fmaf(di, a[i], bias[p8 * 8 + i]), 0.f);
    }
    u16x8 h;
    #pragma unroll
    for (int i = 0; i < 8; ++i) h[i] = f2bf(o[i]);
    *(u16x8*)(xs + r * ROWB + ((p8 ^ (r & 7)) * 16)) = h;
    __syncthreads();

    // ---- phase 2: MFMA (M=32, N=64, K=64)
    const int lane = tid & 63;
    const int w = tid >> 6;
    const int lr = lane & 15;
    const int lk = lane >> 4;
    const int rb = w >> 1;
    const int arow = rb * 16 + lr;

    f32x4 acc[2] = {};
    #pragma unroll
    for (int kb = 0; kb < 2; ++kb) {
        int s = kb * 4 + lk;
        bf16x8 a = *(bf16x8*)(xs + arow * ROWB + ((s ^ (arow & 7)) * 16));
        #pragma unroll
        for (int cc = 0; cc < 2; ++cc) {
            int c = ((w & 1) * 2 + cc) * 16 + lr;
            bf16x8 b = *(bf16x8*)(ws + c * ROWB + ((s ^ (c & 7)) * 16));
            acc[cc] = __builtin_amdgcn_mfma_f32_16x16x32_bf16(a, b, acc[cc], 0, 0, 0);
        }
    }

    int rowbase = nodeBase + rb * 16 + (lk << 2);
    #pragma unroll
    for (int j = 0; j < 4; ++j) {
        int nd = rowbase + j;
        if (nd >= n) continue;
        float dv = dinv[nd];
        #pragma unroll
        for (int cc = 0; cc < 2; ++cc)
            G2[(size_t)nd * 64 + ((w & 1) * 2 + cc) * 16 + lr] = f2bf(acc[cc][j] * dv);
    }
}

// ---- final aggregation (f32 out), 8 lanes/node ---------------------------
__global__ __launch_bounds__(256) void agg_kernel(
    const unsigned short* __restrict__ G, const int2* __restrict__ sedge2,
    const int* __restrict__ nodeStart, const int* __restrict__ nodeCnt,
    const float* __restrict__ dinv, const float* __restrict__ bias,
    float* __restrict__ OUT, int n)
{
    int t = blockIdx.x * blockDim.x + threadIdx.x;
    if (t >= n * 8) return;
    int node = t >> 3, p8 = t & 7;

    f32x8 a = bf8tof(*(const u16x8*)&G[(size_t)node * 64 + p8 * 8]);
    a = gather8(G, sedge2, nodeStart[node], nodeCnt[node], p8, a);

    float di = dinv[node];
    float4 o0, o1;
    o0.x = fmaxf(fmaf(di, a[0], bias[p8 * 8 + 0]), 0.f);
    o0.y = fmaxf(fmaf(di, a[1], bias[p8 * 8 + 1]), 0.f);
    o0.z = fmaxf(fmaf(di, a[2], bias[p8 * 8 + 2]), 0.f);
    o0.w = fmaxf(fmaf(di, a[3], bias[p8 * 8 + 3]), 0.f);
    o1.x = fmaxf(fmaf(di, a[4], bias[p8 * 8 + 4]), 0.f);
    o1.y = fmaxf(fmaf(di, a[5], bias[p8 * 8 + 5]), 0.f);
    o1.z = fmaxf(fmaf(di, a[6], bias[p8 * 8 + 6]), 0.f);
    o1.w = fmaxf(fmaf(di, a[7], bias[p8 * 8 + 7]), 0.f);
    *(float4*)&OUT[(size_t)node * 64 + p8 * 8] = o0;
    *(float4*)&OUT[(size_t)node * 64 + p8 * 8 + 4] = o1;
}

extern "C" void kernel_launch(void* const* d_in, const int* in_sizes, int n_in,
                              void* d_out, int out_size, void* d_ws, size_t ws_size,
                              hipStream_t stream) {
    const float* x     = (const float*)d_in[0];
    const int*   eidx  = (const int*)d_in[1];
    const float* eattr = (const float*)d_in[2];
    const float* W1    = (const float*)d_in[3];
    const float* b1    = (const float*)d_in[4];
    const float* W2    = (const float*)d_in[5];
    const float* b2    = (const float*)d_in[6];
    float* out = (float*)d_out;

    const int n = in_sizes[0] / 128;
    const int E = in_sizes[2];
    const int* row = eidx;
    const int* col = eidx + E;

    const int NBKT = (n + BNODES - 1) / BNODES;    // 196
    const int NEB  = (E + EPB - 1) / EPB;          // 245 (<=256 required)

    int2*  sedge1 = (int2*)d_ws;
    int2*  sedge2 = sedge1 + (size_t)E;
    unsigned short* g1 = (unsigned short*)(sedge2 + (size_t)E);
    unsigned short* g2 = g1 + (size_t)n * 64;
    unsigned short* WT1 = g2 + (size_t)n * 64;
    unsigned short* WT2 = WT1 + 64 * 128;
    float* dinv      = (float*)(WT2 + 64 * 64);
    int*   nodeStart = (int*)(dinv + n);
    int*   nodeCnt   = nodeStart + n;
    int*   H         = nodeCnt + n;
    int*   rowSum    = H + (size_t)NEB * NBKT;
    int*   bktStart  = rowSum + NBKT;

    const int nbG  = (n + 63) / 64;
    const int nbG2 = (n + 31) / 32;
    const int nbA8 = (int)(((size_t)n * 8 + 255) / 256);

    hist_kernel<<<NEB + 48, 256, 0, stream>>>(col, H, E, NBKT, W1, W2, WT1, WT2, NEB);
    rowscan_kernel<<<NBKT, 256, 0, stream>>>(H, rowSum, NEB, NBKT);
    bktscan_kernel<<<1, 256, 0, stream>>>(rowSum, bktStart, NBKT);
    scatter_gemm_kernel<<<NEB + nbG, 256, 0, stream>>>(
        row, col, eattr, H, bktStart, sedge1, E, NBKT, NEB, x, WT1, g1, n);
    fine_kernel<<<NBKT, 512, 0, stream>>>(sedge1, bktStart, sedge2, nodeStart,
                                          nodeCnt, dinv, g1, n);

    aggmm_kernel<<<nbG2, 256, 0, stream>>>(g1, sedge2, nodeStart, nodeCnt, dinv, b1, WT2, g2, n);
    agg_kernel<<<nbA8, 256, 0, stream>>>(g2, sedge2, nodeStart, nodeCnt, dinv, b2, out, n);
}

// Round 13
// 108.867 us; speedup vs baseline: 1.2269x; 1.0331x over previous
//
#include <hip/hip_runtime.h>

// GCN restructure:  deg[c] = 1 + sum_{col=c} w;  dinv = rsqrt(deg)
//   g = (X@W) * dinv[node]        (MFMA bf16; dinv applied late)
//   out[c] = relu( dinv[c] * ( g[c] + sum_{e: col=c} w_e * g[row_e] ) + b )
//
// R13: scatter role shrunk to fit the gemm role's 32KB LDS budget (EPB 3072:
// stage 24KB + tags 3KB + counters 4KB) -> 5 blocks/CU for the whole mixed
// grid (was 3, capped by 41KB).  bktscan launch deleted: scatter and fine
// blocks recompute the 196-value bucket-start scan locally from rowSum.
// Session facts: global atomic ~62B memory-side; 64M LDS atomics = 445us;
// aggs latency-bound on 2-level gather (8-lane/ushort8 + int4 pairs, R12);
// R10: 32-node aggmm blocks for occupancy; R11: LDS-sorted scatter.

#define BNODES 512
#define LB 9
#define MAXBKT 256
#define EPT 12
#define EPB (256 * EPT)      // 3072 edges per sort block; NEB<=512 for E<=1.5M

typedef __attribute__((ext_vector_type(8))) short bf16x8;
typedef __attribute__((ext_vector_type(8))) unsigned short u16x8;
typedef __attribute__((ext_vector_type(8))) float f32x8;
typedef __attribute__((ext_vector_type(4))) float f32x4;

__device__ __forceinline__ unsigned short f2bf(float f) {
    unsigned u = __float_as_uint(f);
    u = (u + 0x7FFF + ((u >> 16) & 1)) >> 16;   // rtne
    return (unsigned short)u;
}
__device__ __forceinline__ float bf2f(unsigned short h) {
    return __uint_as_float(((unsigned)h) << 16);
}
__device__ __forceinline__ f32x8 bf8tof(u16x8 u) {
    f32x8 r;
    #pragma unroll
    for (int i = 0; i < 8; ++i) r[i] = bf2f(u[i]);
    return r;
}

__device__ __forceinline__ int waveIncScan(int v, int lane) {
    #pragma unroll
    for (int d = 1; d < 64; d <<= 1) {
        int u = __shfl_up(v, d, 64);
        if (lane >= d) v += u;
    }
    return v;
}

template<int NW>
__device__ __forceinline__ int blockIncScan(int v, int t, int* wt) {
    int lane = t & 63, w = t >> 6;
    int s = waveIncScan(v, lane);
    if (lane == 63) wt[w] = s;
    __syncthreads();
    int add = 0;
    #pragma unroll
    for (int i = 0; i < NW - 1; ++i) if (i < w) add += wt[i];
    return s + add;
}

// 8-lane/node gather: descriptor pairs via int4, rows via ushort8 (16B/lane).
__device__ __forceinline__ f32x8 gather8(
    const unsigned short* __restrict__ G, const int2* __restrict__ sedge,
    int s, int m, int p8, f32x8 a0)
{
    f32x8 a1 = (f32x8)0.f;
    int e = s, e_end = s + m;
    if ((((unsigned long long)(sedge + e)) & 8) && e < e_end) {
        int2 pk = sedge[e++];
        float w = __int_as_float(pk.y);
        a0 += w * bf8tof(*(const u16x8*)&G[(size_t)pk.x * 64 + p8 * 8]);
    }
    for (; e + 1 < e_end; e += 2) {
        int4 pp = *(const int4*)&sedge[e];
        float w0 = __int_as_float(pp.y);
        float w1 = __int_as_float(pp.w);
        u16x8 g0 = *(const u16x8*)&G[(size_t)pp.x * 64 + p8 * 8];
        u16x8 g1 = *(const u16x8*)&G[(size_t)pp.z * 64 + p8 * 8];
        a0 += w0 * bf8tof(g0);
        a1 += w1 * bf8tof(g1);
    }
    if (e < e_end) {
        int2 pk = sedge[e];
        float w = __int_as_float(pk.y);
        a0 += w * bf8tof(*(const u16x8*)&G[(size_t)pk.x * 64 + p8 * 8]);
    }
    return a0 + a1;
}

// ---- hist (+ weight transpose in tail blocks) ----------------------------

__global__ __launch_bounds__(256) void hist_kernel(
    const int* __restrict__ col, int* __restrict__ H, int E, int NBKT,
    const float* __restrict__ W1, const float* __restrict__ W2,
    unsigned short* __restrict__ WT1, unsigned short* __restrict__ WT2, int NEB)
{
    int t = threadIdx.x, blk = blockIdx.x;
    if (blk >= NEB) {
        int i = (blk - NEB) * 256 + t;
        if (i < 64 * 128) {
            int c = i >> 7, k = i & 127;
            WT1[i] = f2bf(W1[k * 64 + c]);
        } else if (i < 64 * 128 + 64 * 64) {
            int j = i - 64 * 128;
            int c = j >> 6, k = j & 63;
            WT2[j] = f2bf(W2[k * 64 + c]);
        }
        return;
    }
    __shared__ int h[MAXBKT];
    for (int b = t; b < NBKT; b += 256) h[b] = 0;
    __syncthreads();
    int base = blk * EPB;
    #pragma unroll
    for (int i = 0; i < EPT; ++i) {
        int e = base + i * 256 + t;
        if (e < E) atomicAdd(&h[col[e] >> LB], 1);
    }
    __syncthreads();
    for (int b = t; b < NBKT; b += 256) H[blk * NBKT + b] = h[b];
}

// per-bucket exclusive scan over block counts (NEB <= 512), 512 threads
__global__ __launch_bounds__(512) void rowscan_kernel(
    int* __restrict__ H, int* __restrict__ rowSum, int NEB, int NBKT)
{
    __shared__ int wt[8];
    int b = blockIdx.x, t = threadIdx.x;
    int v = (t < NEB) ? H[t * NBKT + b] : 0;
    int incl = blockIncScan<8>(v, t, wt);
    if (t < NEB) H[t * NBKT + b] = incl - v;
    if (t == 511) rowSum[b] = incl;
}

// ---- merged (LDS-sorted scatter) + (layer-1 MFMA GEMM, unscaled) ---------
// Both roles fit 32KB static LDS -> 5 blocks/CU.
__global__ __launch_bounds__(256) void scatter_gemm_kernel(
    const int* __restrict__ row, const int* __restrict__ col,
    const float* __restrict__ w, const int* __restrict__ H,
    const int* __restrict__ rowSum, int2* __restrict__ sedge1,
    int E, int NBKT, int NEB,
    const float* __restrict__ X, const unsigned short* __restrict__ WT,
    unsigned short* __restrict__ G, int n)
{
    __shared__ __align__(16) char smem[32768];
    const int t = threadIdx.x;
    const int blk = blockIdx.x;

    if (blk < NEB) {
        // layout: stage 24576 | bstage 3072 | lcnt/loff/lcur/gbase 4*1024 | wt 32
        int2* stage = (int2*)smem;
        unsigned char* bstage = (unsigned char*)(stage + EPB);
        int* lcnt  = (int*)(bstage + EPB);
        int* loff  = lcnt + MAXBKT;
        int* lcur  = loff + MAXBKT;
        int* gbase = lcur + MAXBKT;
        int* wt    = gbase + MAXBKT;

        // bucket-start scan (local, replaces bktscan kernel)
        int vb = (t < NBKT) ? rowSum[t] : 0;
        int ib = blockIncScan<4>(vb, t, wt);
        if (t < NBKT) gbase[t] = (ib - vb) + H[blk * NBKT + t];
        for (int b = t; b < NBKT; b += 256) lcnt[b] = 0;
        __syncthreads();

        int base = blk * EPB;
        #pragma unroll
        for (int i = 0; i < EPT; ++i) {
            int e = base + i * 256 + t;
            if (e < E) atomicAdd(&lcnt[col[e] >> LB], 1);
        }
        __syncthreads();
        int v = (t < NBKT) ? lcnt[t] : 0;
        int incl = blockIncScan<4>(v, t, wt);
        if (t < NBKT) {
            int x0 = incl - v;
            loff[t] = x0;
            lcur[t] = x0;
        }
        __syncthreads();
        #pragma unroll
        for (int i = 0; i < EPT; ++i) {
            int e = base + i * 256 + t;
            if (e < E) {
                int c = col[e];
                int b = c >> LB;
                int pos = atomicAdd(&lcur[b], 1);    // LDS atomic
                int2 pk;
                pk.x = row[e] | ((c & (BNODES - 1)) << 20);
                pk.y = __float_as_int(w[e]);
                stage[pos] = pk;
                bstage[pos] = (unsigned char)b;
            }
        }
        __syncthreads();
        int ecnt = E - base; if (ecnt > EPB) ecnt = EPB;
        for (int i = t; i < ecnt; i += 256) {
            int b = bstage[i];
            int g = gbase[b] + (i - loff[b]);
            sedge1[g] = stage[i];
        }
        return;
    }

    // gemm role (K=128, f32 in, unscaled bf16 out): xs 16KB | ws 16KB
    constexpr int K = 128, ROWB = 256, SLOTS = 16, CPR = 32;
    char* xs = smem;
    char* ws = smem + 64 * ROWB;
    const int nodeBase = (blk - NEB) * 64;

    for (int q = t; q < 64 * SLOTS; q += 256) {
        int r = q / SLOTS, s = q % SLOTS;
        uint4 v = *(const uint4*)(WT + r * K + s * 8);
        *(uint4*)(ws + r * ROWB + ((s ^ (r & 7)) * 16)) = v;
    }
    for (int q = t; q < 64 * CPR; q += 256) {
        int r = q / CPR, c = q % CPR;
        int node = nodeBase + r;
        float4 v = make_float4(0.f, 0.f, 0.f, 0.f);
        if (node < n) v = *(const float4*)(X + (size_t)node * K + c * 4);
        ushort4 h;
        h.x = f2bf(v.x); h.y = f2bf(v.y); h.z = f2bf(v.z); h.w = f2bf(v.w);
        *(ushort4*)(xs + r * ROWB + (((c >> 1) ^ (r & 7)) * 16) + (c & 1) * 8) = h;
    }
    __syncthreads();

    const int lane = t & 63;
    const int wv = t >> 6;
    const int lr = lane & 15;
    const int lk = lane >> 4;
    const int arow = (wv << 4) + lr;

    f32x4 acc[4] = {};
    #pragma unroll
    for (int kb = 0; kb < 4; ++kb) {
        int s = kb * 4 + lk;
        bf16x8 a = *(bf16x8*)(xs + arow * ROWB + ((s ^ (arow & 7)) * 16));
        #pragma unroll
        for (int cb = 0; cb < 4; ++cb) {
            int c = cb * 16 + lr;
            bf16x8 b = *(bf16x8*)(ws + c * ROWB + ((s ^ (c & 7)) * 16));
            acc[cb] = __builtin_amdgcn_mfma_f32_16x16x32_bf16(a, b, acc[cb], 0, 0, 0);
        }
    }

    int rowbase = nodeBase + (wv << 4) + (lk << 2);
    #pragma unroll
    for (int j = 0; j < 4; ++j) {
        int node = rowbase + j;
        if (node >= n) continue;
        #pragma unroll
        for (int cb = 0; cb < 4; ++cb)
            G[(size_t)node * 64 + cb * 16 + lr] = f2bf(acc[cb][j]);
    }
}

// ---- fine: 512-node bucket -> per-node CSR + dinv + scale own g1 rows ----
__global__ __launch_bounds__(512) void fine_kernel(
    const int2* __restrict__ sedge1, const int* __restrict__ rowSum,
    int2* __restrict__ sedge2, int* __restrict__ nodeStart,
    int* __restrict__ nodeCnt, float* __restrict__ dinv,
    unsigned short* __restrict__ g1, int n, int NBKT)
{
    __shared__ int cnt[BNODES];
    __shared__ float wsum[BNODES];
    __shared__ int off[BNODES];
    __shared__ int cur[BNODES];
    __shared__ float dloc[BNODES];
    __shared__ int bs[MAXBKT + 1];
    __shared__ int wt[8];
    int b = blockIdx.x, t = threadIdx.x;

    // bucket-start scan (local, replaces bktscan kernel)
    int vb = (t < NBKT) ? rowSum[t] : 0;
    int ib = blockIncScan<8>(vb, t, wt);
    if (t < NBKT) bs[t] = ib - vb;
    if (t == 511) bs[NBKT] = ib;
    cnt[t] = 0; wsum[t] = 1.0f;
    __syncthreads();

    int s = bs[b], e = (b + 1 <= NBKT) ? bs[b + 1] : bs[NBKT];
    for (int j = s + t; j < e; j += 512) {
        int2 pk = sedge1[j];
        int ld = pk.x >> 20;
        atomicAdd(&cnt[ld], 1);
        atomicAdd(&wsum[ld], __int_as_float(pk.y));
    }
    __syncthreads();
    int v = cnt[t];
    int incl = blockIncScan<8>(v, t, wt);
    int x0 = s + incl - v;
    off[t] = x0;
    cur[t] = x0;
    dloc[t] = rsqrtf(wsum[t]);
    __syncthreads();
    int node = b * BNODES + t;
    if (node < n) {
        nodeStart[node] = off[t];
        nodeCnt[node] = cnt[t];
        dinv[node] = dloc[t];
    }
    for (int j = s + t; j < e; j += 512) {
        int2 pk = sedge1[j];
        int ld = pk.x >> 20;
        int pos = atomicAdd(&cur[ld], 1);
        sedge2[pos] = make_int2(pk.x & 0xFFFFF, pk.y);
    }
    for (int q = t; q < BNODES * 8; q += 512) {
        int r = q >> 3, cc = q & 7;
        int nd = b * BNODES + r;
        if (nd >= n) continue;
        float dv = dloc[r];
        size_t offb = (size_t)nd * 64 + cc * 8;
        ushort4 u0 = *(const ushort4*)(g1 + offb);
        ushort4 u1 = *(const ushort4*)(g1 + offb + 4);
        u0.x = f2bf(bf2f(u0.x) * dv); u0.y = f2bf(bf2f(u0.y) * dv);
        u0.z = f2bf(bf2f(u0.z) * dv); u0.w = f2bf(bf2f(u0.w) * dv);
        u1.x = f2bf(bf2f(u1.x) * dv); u1.y = f2bf(bf2f(u1.y) * dv);
        u1.z = f2bf(bf2f(u1.z) * dv); u1.w = f2bf(bf2f(u1.w) * dv);
        *(ushort4*)(g1 + offb) = u0;
        *(ushort4*)(g1 + offb + 4) = u1;
    }
}

// ---- FUSED agg1 + gemm2, 32 nodes/block, single-pass 8-lane agg ----------
__global__ __launch_bounds__(256) void aggmm_kernel(
    const unsigned short* __restrict__ G1, const int2* __restrict__ sedge2,
    const int* __restrict__ nodeStart, const int* __restrict__ nodeCnt,
    const float* __restrict__ dinv, const float* __restrict__ bias,
    const unsigned short* __restrict__ WT2, unsigned short* __restrict__ G2, int n)
{
    constexpr int BN = 32;
    constexpr int ROWB = 128;
    __shared__ char smem[(BN + 64) * ROWB];   // act (4KB) | ws (8KB)
    char* xs = smem;
    char* ws = smem + BN * ROWB;
    const int tid = threadIdx.x;
    const int nodeBase = blockIdx.x * BN;

    for (int q = tid; q < 64 * 8; q += 256) {
        int r = q >> 3, s = q & 7;
        uint4 v = *(const uint4*)(WT2 + r * 64 + s * 8);
        *(uint4*)(ws + r * ROWB + ((s ^ (r & 7)) * 16)) = v;
    }

    int p8 = tid & 7;
    int r = tid >> 3;
    int node = nodeBase + r;
    f32x8 o = (f32x8)0.f;
    if (node < n) {
        f32x8 a = bf8tof(*(const u16x8*)&G1[(size_t)node * 64 + p8 * 8]);
        a = gather8(G1, sedge2, nodeStart[node], nodeCnt[node], p8, a);
        float di = dinv[node];
        #pragma unroll
        for (int i = 0; i < 8; ++i)
            o[i] = fmaxf(fmaf(di, a[i], bias[p8 * 8 + i]), 0.f);
    }
    u16x8 h;
    #pragma unroll
    for (int i = 0; i < 8; ++i) h[i] = f2bf(o[i]);
    *(u16x8*)(xs + r * ROWB + ((p8 ^ (r & 7)) * 16)) = h;
    __syncthreads();

    const int lane = tid & 63;
    const int w = tid >> 6;
    const int lr = lane & 15;
    const int lk = lane >> 4;
    const int rb = w >> 1;
    const int arow = rb * 16 + lr;

    f32x4 acc[2] = {};
    #pragma unroll
    for (int kb = 0; kb < 2; ++kb) {
        int s = kb * 4 + lk;
        bf16x8 a = *(bf16x8*)(xs + arow * ROWB + ((s ^ (arow & 7)) * 16));
        #pragma unroll
        for (int cc = 0; cc < 2; ++cc) {
            int c = ((w & 1) * 2 + cc) * 16 + lr;
            bf16x8 b = *(bf16x8*)(ws + c * ROWB + ((s ^ (c & 7)) * 16));
            acc[cc] = __builtin_amdgcn_mfma_f32_16x16x32_bf16(a, b, acc[cc], 0, 0, 0);
        }
    }

    int rowbase = nodeBase + rb * 16 + (lk << 2);
    #pragma unroll
    for (int j = 0; j < 4; ++j) {
        int nd = rowbase + j;
        if (nd >= n) continue;
        float dv = dinv[nd];
        #pragma unroll
        for (int cc = 0; cc < 2; ++cc)
            G2[(size_t)nd * 64 + ((w & 1) * 2 + cc) * 16 + lr] = f2bf(acc[cc][j] * dv);
    }
}

// ---- final aggregation (f32 out), 8 lanes/node ---------------------------
__global__ __launch_bounds__(256) void agg_kernel(
    const unsigned short* __restrict__ G, const int2* __restrict__ sedge2,
    const int* __restrict__ nodeStart, const int* __restrict__ nodeCnt,
    const float* __restrict__ dinv, const float* __restrict__ bias,
    float* __restrict__ OUT, int n)
{
    int t = blockIdx.x * blockDim.x + threadIdx.x;
    if (t >= n * 8) return;
    int node = t >> 3, p8 = t & 7;

    f32x8 a = bf8tof(*(const u16x8*)&G[(size_t)node * 64 + p8 * 8]);
    a = gather8(G, sedge2, nodeStart[node], nodeCnt[node], p8, a);

    float di = dinv[node];
    float4 o0, o1;
    o0.x = fmaxf(fmaf(di, a[0], bias[p8 * 8 + 0]), 0.f);
    o0.y = fmaxf(fmaf(di, a[1], bias[p8 * 8 + 1]), 0.f);
    o0.z = fmaxf(fmaf(di, a[2], bias[p8 * 8 + 2]), 0.f);
    o0.w = fmaxf(fmaf(di, a[3], bias[p8 * 8 + 3]), 0.f);
    o1.x = fmaxf(fmaf(di, a[4], bias[p8 * 8 + 4]), 0.f);
    o1.y = fmaxf(fmaf(di, a[5], bias[p8 * 8 + 5]), 0.f);
    o1.z = fmaxf(fmaf(di, a[6], bias[p8 * 8 + 6]), 0.f);
    o1.w = fmaxf(fmaf(di, a[7], bias[p8 * 8 + 7]), 0.f);
    *(float4*)&OUT[(size_t)node * 64 + p8 * 8] = o0;
    *(float4*)&OUT[(size_t)node * 64 + p8 * 8 + 4] = o1;
}

extern "C" void kernel_launch(void* const* d_in, const int* in_sizes, int n_in,
                              void* d_out, int out_size, void* d_ws, size_t ws_size,
                              hipStream_t stream) {
    const float* x     = (const float*)d_in[0];
    const int*   eidx  = (const int*)d_in[1];
    const float* eattr = (const float*)d_in[2];
    const float* W1    = (const float*)d_in[3];
    const float* b1    = (const float*)d_in[4];
    const float* W2    = (const float*)d_in[5];
    const float* b2    = (const float*)d_in[6];
    float* out = (float*)d_out;

    const int n = in_sizes[0] / 128;
    const int E = in_sizes[2];
    const int* row = eidx;
    const int* col = eidx + E;

    const int NBKT = (n + BNODES - 1) / BNODES;    // 196
    const int NEB  = (E + EPB - 1) / EPB;          // 326 (<=512 required)

    int2*  sedge1 = (int2*)d_ws;
    int2*  sedge2 = sedge1 + (size_t)E;
    unsigned short* g1 = (unsigned short*)(sedge2 + (size_t)E);
    unsigned short* g2 = g1 + (size_t)n * 64;
    unsigned short* WT1 = g2 + (size_t)n * 64;
    unsigned short* WT2 = WT1 + 64 * 128;
    float* dinv      = (float*)(WT2 + 64 * 64);
    int*   nodeStart = (int*)(dinv + n);
    int*   nodeCnt   = nodeStart + n;
    int*   H         = nodeCnt + n;
    int*   rowSum    = H + (size_t)NEB * NBKT;

    const int nbG  = (n + 63) / 64;
    const int nbG2 = (n + 31) / 32;
    const int nbA8 = (int)(((size_t)n * 8 + 255) / 256);

    hist_kernel<<<NEB + 48, 256, 0, stream>>>(col, H, E, NBKT, W1, W2, WT1, WT2, NEB);
    rowscan_kernel<<<NBKT, 512, 0, stream>>>(H, rowSum, NEB, NBKT);
    scatter_gemm_kernel<<<NEB + nbG, 256, 0, stream>>>(
        row, col, eattr, H, rowSum, sedge1, E, NBKT, NEB, x, WT1, g1, n);
    fine_kernel<<<NBKT, 512, 0, stream>>>(sedge1, rowSum, sedge2, nodeStart,
                                          nodeCnt, dinv, g1, n, NBKT);

    aggmm_kernel<<<nbG2, 256, 0, stream>>>(g1, sedge2, nodeStart, nodeCnt, dinv, b1, WT2, g2, n);
    agg_kernel<<<nbA8, 256, 0, stream>>>(g2, sedge2, nodeStart, nodeCnt, dinv, b2, out, n);
}

// Round 14
// 108.841 us; speedup vs baseline: 1.2272x; 1.0002x over previous
//
#include <hip/hip_runtime.h>

// GCN:  w'_e = dinv[row]*w*dinv[col]  (folded normalization, shared by BOTH
// layers);  g = X@W UNSCALED (MFMA bf16);
//   out[c] = relu( dinv[c]^2 * g[c] + sum_e w'_e * g[row_e] + b )
//
// R14: normalization folded into edge weights -> fine's 25.6MB g1 scale pass
// deleted; fine split into fine_dinv (degree+scan) and fine_csr (CSR scatter
// with w', dinv[row] gathered from the L2-resident 400KB table).  Epilogues
// lose their dinv multiplies.  Everything else R13-proven.
// Session facts: global atomic ~62B memory-side; 64M LDS atomics = 445us;
// aggs at ~L3-BW/latency floor (128MB row reads/layer, 8-lane ushort8 +
// int4 descriptor pairs); 32KB LDS cap -> 5 blocks/CU mixed grid.

#define BNODES 512
#define LB 9
#define MAXBKT 256
#define EPT 12
#define EPB (256 * EPT)      // 3072 edges per sort block; NEB<=512 for E<=1.5M

typedef __attribute__((ext_vector_type(8))) short bf16x8;
typedef __attribute__((ext_vector_type(8))) unsigned short u16x8;
typedef __attribute__((ext_vector_type(8))) float f32x8;
typedef __attribute__((ext_vector_type(4))) float f32x4;

__device__ __forceinline__ unsigned short f2bf(float f) {
    unsigned u = __float_as_uint(f);
    u = (u + 0x7FFF + ((u >> 16) & 1)) >> 16;   // rtne
    return (unsigned short)u;
}
__device__ __forceinline__ float bf2f(unsigned short h) {
    return __uint_as_float(((unsigned)h) << 16);
}
__device__ __forceinline__ f32x8 bf8tof(u16x8 u) {
    f32x8 r;
    #pragma unroll
    for (int i = 0; i < 8; ++i) r[i] = bf2f(u[i]);
    return r;
}

__device__ __forceinline__ int waveIncScan(int v, int lane) {
    #pragma unroll
    for (int d = 1; d < 64; d <<= 1) {
        int u = __shfl_up(v, d, 64);
        if (lane >= d) v += u;
    }
    return v;
}

template<int NW>
__device__ __forceinline__ int blockIncScan(int v, int t, int* wt) {
    int lane = t & 63, w = t >> 6;
    int s = waveIncScan(v, lane);
    if (lane == 63) wt[w] = s;
    __syncthreads();
    int add = 0;
    #pragma unroll
    for (int i = 0; i < NW - 1; ++i) if (i < w) add += wt[i];
    return s + add;
}

// 8-lane/node gather: descriptor pairs via int4, rows via ushort8 (16B/lane).
__device__ __forceinline__ f32x8 gather8(
    const unsigned short* __restrict__ G, const int2* __restrict__ sedge,
    int s, int m, int p8, f32x8 a0)
{
    f32x8 a1 = (f32x8)0.f;
    int e = s, e_end = s + m;
    if ((((unsigned long long)(sedge + e)) & 8) && e < e_end) {
        int2 pk = sedge[e++];
        float w = __int_as_float(pk.y);
        a0 += w * bf8tof(*(const u16x8*)&G[(size_t)pk.x * 64 + p8 * 8]);
    }
    for (; e + 1 < e_end; e += 2) {
        int4 pp = *(const int4*)&sedge[e];
        float w0 = __int_as_float(pp.y);
        float w1 = __int_as_float(pp.w);
        u16x8 g0 = *(const u16x8*)&G[(size_t)pp.x * 64 + p8 * 8];
        u16x8 g1 = *(const u16x8*)&G[(size_t)pp.z * 64 + p8 * 8];
        a0 += w0 * bf8tof(g0);
        a1 += w1 * bf8tof(g1);
    }
    if (e < e_end) {
        int2 pk = sedge[e];
        float w = __int_as_float(pk.y);
        a0 += w * bf8tof(*(const u16x8*)&G[(size_t)pk.x * 64 + p8 * 8]);
    }
    return a0 + a1;
}

// ---- hist (+ weight transpose in tail blocks) ----------------------------

__global__ __launch_bounds__(256) void hist_kernel(
    const int* __restrict__ col, int* __restrict__ H, int E, int NBKT,
    const float* __restrict__ W1, const float* __restrict__ W2,
    unsigned short* __restrict__ WT1, unsigned short* __restrict__ WT2, int NEB)
{
    int t = threadIdx.x, blk = blockIdx.x;
    if (blk >= NEB) {
        int i = (blk - NEB) * 256 + t;
        if (i < 64 * 128) {
            int c = i >> 7, k = i & 127;
            WT1[i] = f2bf(W1[k * 64 + c]);
        } else if (i < 64 * 128 + 64 * 64) {
            int j = i - 64 * 128;
            int c = j >> 6, k = j & 63;
            WT2[j] = f2bf(W2[k * 64 + c]);
        }
        return;
    }
    __shared__ int h[MAXBKT];
    for (int b = t; b < NBKT; b += 256) h[b] = 0;
    __syncthreads();
    int base = blk * EPB;
    #pragma unroll
    for (int i = 0; i < EPT; ++i) {
        int e = base + i * 256 + t;
        if (e < E) atomicAdd(&h[col[e] >> LB], 1);
    }
    __syncthreads();
    for (int b = t; b < NBKT; b += 256) H[blk * NBKT + b] = h[b];
}

__global__ __launch_bounds__(512) void rowscan_kernel(
    int* __restrict__ H, int* __restrict__ rowSum, int NEB, int NBKT)
{
    __shared__ int wt[8];
    int b = blockIdx.x, t = threadIdx.x;
    int v = (t < NEB) ? H[t * NBKT + b] : 0;
    int incl = blockIncScan<8>(v, t, wt);
    if (t < NEB) H[t * NBKT + b] = incl - v;
    if (t == 511) rowSum[b] = incl;
}

// ---- merged (LDS-sorted scatter) + (layer-1 MFMA GEMM, unscaled) ---------
__global__ __launch_bounds__(256) void scatter_gemm_kernel(
    const int* __restrict__ row, const int* __restrict__ col,
    const float* __restrict__ w, const int* __restrict__ H,
    const int* __restrict__ rowSum, int2* __restrict__ sedge1,
    int E, int NBKT, int NEB,
    const float* __restrict__ X, const unsigned short* __restrict__ WT,
    unsigned short* __restrict__ G, int n)
{
    __shared__ __align__(16) char smem[32768];
    const int t = threadIdx.x;
    const int blk = blockIdx.x;

    if (blk < NEB) {
        int2* stage = (int2*)smem;
        unsigned char* bstage = (unsigned char*)(stage + EPB);
        int* lcnt  = (int*)(bstage + EPB);
        int* loff  = lcnt + MAXBKT;
        int* lcur  = loff + MAXBKT;
        int* gbase = lcur + MAXBKT;
        int* wt    = gbase + MAXBKT;

        int vb = (t < NBKT) ? rowSum[t] : 0;
        int ib = blockIncScan<4>(vb, t, wt);
        if (t < NBKT) gbase[t] = (ib - vb) + H[blk * NBKT + t];
        for (int b = t; b < NBKT; b += 256) lcnt[b] = 0;
        __syncthreads();

        int base = blk * EPB;
        #pragma unroll
        for (int i = 0; i < EPT; ++i) {
            int e = base + i * 256 + t;
            if (e < E) atomicAdd(&lcnt[col[e] >> LB], 1);
        }
        __syncthreads();
        int v = (t < NBKT) ? lcnt[t] : 0;
        int incl = blockIncScan<4>(v, t, wt);
        if (t < NBKT) {
            int x0 = incl - v;
            loff[t] = x0;
            lcur[t] = x0;
        }
        __syncthreads();
        #pragma unroll
        for (int i = 0; i < EPT; ++i) {
            int e = base + i * 256 + t;
            if (e < E) {
                int c = col[e];
                int b = c >> LB;
                int pos = atomicAdd(&lcur[b], 1);    // LDS atomic
                int2 pk;
                pk.x = row[e] | ((c & (BNODES - 1)) << 20);
                pk.y = __float_as_int(w[e]);
                stage[pos] = pk;
                bstage[pos] = (unsigned char)b;
            }
        }
        __syncthreads();
        int ecnt = E - base; if (ecnt > EPB) ecnt = EPB;
        for (int i = t; i < ecnt; i += 256) {
            int b = bstage[i];
            int g = gbase[b] + (i - loff[b]);
            sedge1[g] = stage[i];
        }
        return;
    }

    constexpr int K = 128, ROWB = 256, SLOTS = 16, CPR = 32;
    char* xs = smem;
    char* ws = smem + 64 * ROWB;
    const int nodeBase = (blk - NEB) * 64;

    for (int q = t; q < 64 * SLOTS; q += 256) {
        int r = q / SLOTS, s = q % SLOTS;
        uint4 v = *(const uint4*)(WT + r * K + s * 8);
        *(uint4*)(ws + r * ROWB + ((s ^ (r & 7)) * 16)) = v;
    }
    for (int q = t; q < 64 * CPR; q += 256) {
        int r = q / CPR, c = q % CPR;
        int node = nodeBase + r;
        float4 v = make_float4(0.f, 0.f, 0.f, 0.f);
        if (node < n) v = *(const float4*)(X + (size_t)node * K + c * 4);
        ushort4 h;
        h.x = f2bf(v.x); h.y = f2bf(v.y); h.z = f2bf(v.z); h.w = f2bf(v.w);
        *(ushort4*)(xs + r * ROWB + (((c >> 1) ^ (r & 7)) * 16) + (c & 1) * 8) = h;
    }
    __syncthreads();

    const int lane = t & 63;
    const int wv = t >> 6;
    const int lr = lane & 15;
    const int lk = lane >> 4;
    const int arow = (wv << 4) + lr;

    f32x4 acc[4] = {};
    #pragma unroll
    for (int kb = 0; kb < 4; ++kb) {
        int s = kb * 4 + lk;
        bf16x8 a = *(bf16x8*)(xs + arow * ROWB + ((s ^ (arow & 7)) * 16));
        #pragma unroll
        for (int cb = 0; cb < 4; ++cb) {
            int c = cb * 16 + lr;
            bf16x8 b = *(bf16x8*)(ws + c * ROWB + ((s ^ (c & 7)) * 16));
            acc[cb] = __builtin_amdgcn_mfma_f32_16x16x32_bf16(a, b, acc[cb], 0, 0, 0);
        }
    }

    int rowbase = nodeBase + (wv << 4) + (lk << 2);
    #pragma unroll
    for (int j = 0; j < 4; ++j) {
        int node = rowbase + j;
        if (node >= n) continue;
        #pragma unroll
        for (int cb = 0; cb < 4; ++cb)
            G[(size_t)node * 64 + cb * 16 + lr] = f2bf(acc[cb][j]);
    }
}

// ---- fine_dinv: per-bucket degree + scan -> nodeStart/nodeCnt/dinv -------
__global__ __launch_bounds__(512) void fine_dinv_kernel(
    const int2* __restrict__ sedge1, const int* __restrict__ rowSum,
    int* __restrict__ nodeStart, int* __restrict__ nodeCnt,
    float* __restrict__ dinv, int n, int NBKT)
{
    __shared__ int cnt[BNODES];
    __shared__ float wsum[BNODES];
    __shared__ int bs[MAXBKT + 1];
    __shared__ int wt[8];
    int b = blockIdx.x, t = threadIdx.x;

    int vb = (t < NBKT) ? rowSum[t] : 0;
    int ib = blockIncScan<8>(vb, t, wt);
    if (t < NBKT) bs[t] = ib - vb;
    if (t == 511) bs[NBKT] = ib;
    cnt[t] = 0; wsum[t] = 1.0f;
    __syncthreads();

    int s = bs[b], e = bs[b + 1];
    for (int j = s + t; j < e; j += 512) {
        int2 pk = sedge1[j];
        int ld = pk.x >> 20;
        atomicAdd(&cnt[ld], 1);
        atomicAdd(&wsum[ld], __int_as_float(pk.y));
    }
    __syncthreads();
    int v = cnt[t];
    int incl = blockIncScan<8>(v, t, wt);
    int x0 = s + incl - v;
    int node = b * BNODES + t;
    if (node < n) {
        nodeStart[node] = x0;
        nodeCnt[node] = v;
        dinv[node] = rsqrtf(wsum[t]);
    }
}

// ---- fine_csr: CSR scatter with folded weights w' = dinv[row]*w*dinv[col] -
__global__ __launch_bounds__(512) void fine_csr_kernel(
    const int2* __restrict__ sedge1, const int* __restrict__ rowSum,
    const int* __restrict__ nodeStart, const float* __restrict__ dinv,
    int2* __restrict__ sedge2, int n, int NBKT)
{
    __shared__ int cur[BNODES];
    __shared__ float dloc[BNODES];
    __shared__ int bs[MAXBKT + 1];
    __shared__ int wt[8];
    int b = blockIdx.x, t = threadIdx.x;

    int vb = (t < NBKT) ? rowSum[t] : 0;
    int ib = blockIncScan<8>(vb, t, wt);
    if (t < NBKT) bs[t] = ib - vb;
    if (t == 511) bs[NBKT] = ib;
    int node = b * BNODES + t;
    cur[t]  = (node < n) ? nodeStart[node] : 0;
    dloc[t] = (node < n) ? dinv[node] : 0.f;
    __syncthreads();

    int s = bs[b], e = bs[b + 1];
    for (int j = s + t; j < e; j += 512) {
        int2 pk = sedge1[j];
        int ld = pk.x >> 20;
        int rw = pk.x & 0xFFFFF;
        int pos = atomicAdd(&cur[ld], 1);            // LDS atomic
        float wp = __int_as_float(pk.y) * dinv[rw] * dloc[ld];
        sedge2[pos] = make_int2(rw, __float_as_int(wp));
    }
}

// ---- FUSED agg1 + gemm2, 32 nodes/block, single-pass 8-lane agg ----------
__global__ __launch_bounds__(256) void aggmm_kernel(
    const unsigned short* __restrict__ G1, const int2* __restrict__ sedge2,
    const int* __restrict__ nodeStart, const int* __restrict__ nodeCnt,
    const float* __restrict__ dinv, const float* __restrict__ bias,
    const unsigned short* __restrict__ WT2, unsigned short* __restrict__ G2, int n)
{
    constexpr int BN = 32;
    constexpr int ROWB = 128;
    __shared__ char smem[(BN + 64) * ROWB];   // act (4KB) | ws (8KB)
    char* xs = smem;
    char* ws = smem + BN * ROWB;
    const int tid = threadIdx.x;
    const int nodeBase = blockIdx.x * BN;

    for (int q = tid; q < 64 * 8; q += 256) {
        int r = q >> 3, s = q & 7;
        uint4 v = *(const uint4*)(WT2 + r * 64 + s * 8);
        *(uint4*)(ws + r * ROWB + ((s ^ (r & 7)) * 16)) = v;
    }

    int p8 = tid & 7;
    int r = tid >> 3;
    int node = nodeBase + r;
    f32x8 o = (f32x8)0.f;
    if (node < n) {
        float di = dinv[node];
        f32x8 a = (di * di) * bf8tof(*(const u16x8*)&G1[(size_t)node * 64 + p8 * 8]);
        a = gather8(G1, sedge2, nodeStart[node], nodeCnt[node], p8, a);
        #pragma unroll
        for (int i = 0; i < 8; ++i)
            o[i] = fmaxf(a[i] + bias[p8 * 8 + i], 0.f);
    }
    u16x8 h;
    #pragma unroll
    for (int i = 0; i < 8; ++i) h[i] = f2bf(o[i]);
    *(u16x8*)(xs + r * ROWB + ((p8 ^ (r & 7)) * 16)) = h;
    __syncthreads();

    const int lane = tid & 63;
    const int w = tid >> 6;
    const int lr = lane & 15;
    const int lk = lane >> 4;
    const int rb = w >> 1;
    const int arow = rb * 16 + lr;

    f32x4 acc[2] = {};
    #pragma unroll
    for (int kb = 0; kb < 2; ++kb) {
        int s = kb * 4 + lk;
        bf16x8 a = *(bf16x8*)(xs + arow * ROWB + ((s ^ (arow & 7)) * 16));
        #pragma unroll
        for (int cc = 0; cc < 2; ++cc) {
            int c = ((w & 1) * 2 + cc) * 16 + lr;
            bf16x8 b = *(bf16x8*)(ws + c * ROWB + ((s ^ (c & 7)) * 16));
            acc[cc] = __builtin_amdgcn_mfma_f32_16x16x32_bf16(a, b, acc[cc], 0, 0, 0);
        }
    }

    // g2 written UNSCALED (normalization folded into w' and self-term)
    int rowbase = nodeBase + rb * 16 + (lk << 2);
    #pragma unroll
    for (int j = 0; j < 4; ++j) {
        int nd = rowbase + j;
        if (nd >= n) continue;
        #pragma unroll
        for (int cc = 0; cc < 2; ++cc)
            G2[(size_t)nd * 64 + ((w & 1) * 2 + cc) * 16 + lr] = f2bf(acc[cc][j]);
    }
}

// ---- final aggregation (f32 out), 8 lanes/node ---------------------------
__global__ __launch_bounds__(256) void agg_kernel(
    const unsigned short* __restrict__ G, const int2* __restrict__ sedge2,
    const int* __restrict__ nodeStart, const int* __restrict__ nodeCnt,
    const float* __restrict__ dinv, const float* __restrict__ bias,
    float* __restrict__ OUT, int n)
{
    int t = blockIdx.x * blockDim.x + threadIdx.x;
    if (t >= n * 8) return;
    int node = t >> 3, p8 = t & 7;

    float di = dinv[node];
    f32x8 a = (di * di) * bf8tof(*(const u16x8*)&G[(size_t)node * 64 + p8 * 8]);
    a = gather8(G, sedge2, nodeStart[node], nodeCnt[node], p8, a);

    float4 o0, o1;
    o0.x = fmaxf(a[0] + bias[p8 * 8 + 0], 0.f);
    o0.y = fmaxf(a[1] + bias[p8 * 8 + 1], 0.f);
    o0.z = fmaxf(a[2] + bias[p8 * 8 + 2], 0.f);
    o0.w = fmaxf(a[3] + bias[p8 * 8 + 3], 0.f);
    o1.x = fmaxf(a[4] + bias[p8 * 8 + 4], 0.f);
    o1.y = fmaxf(a[5] + bias[p8 * 8 + 5], 0.f);
    o1.z = fmaxf(a[6] + bias[p8 * 8 + 6], 0.f);
    o1.w = fmaxf(a[7] + bias[p8 * 8 + 7], 0.f);
    *(float4*)&OUT[(size_t)node * 64 + p8 * 8] = o0;
    *(float4*)&OUT[(size_t)node * 64 + p8 * 8 + 4] = o1;
}

extern "C" void kernel_launch(void* const* d_in, const int* in_sizes, int n_in,
                              void* d_out, int out_size, void* d_ws, size_t ws_size,
                              hipStream_t stream) {
    const float* x     = (const float*)d_in[0];
    const int*   eidx  = (const int*)d_in[1];
    const float* eattr = (const float*)d_in[2];
    const float* W1    = (const float*)d_in[3];
    const float* b1    = (const float*)d_in[4];
    const float* W2    = (const float*)d_in[5];
    const float* b2    = (const float*)d_in[6];
    float* out = (float*)d_out;

    const int n = in_sizes[0] / 128;
    const int E = in_sizes[2];
    const int* row = eidx;
    const int* col = eidx + E;

    const int NBKT = (n + BNODES - 1) / BNODES;    // 196
    const int NEB  = (E + EPB - 1) / EPB;          // 326 (<=512 required)

    int2*  sedge1 = (int2*)d_ws;
    int2*  sedge2 = sedge1 + (size_t)E;
    unsigned short* g1 = (unsigned short*)(sedge2 + (size_t)E);
    unsigned short* g2 = g1 + (size_t)n * 64;
    unsigned short* WT1 = g2 + (size_t)n * 64;
    unsigned short* WT2 = WT1 + 64 * 128;
    float* dinv      = (float*)(WT2 + 64 * 64);
    int*   nodeStart = (int*)(dinv + n);
    int*   nodeCnt   = nodeStart + n;
    int*   H         = nodeCnt + n;
    int*   rowSum    = H + (size_t)NEB * NBKT;

    const int nbG  = (n + 63) / 64;
    const int nbG2 = (n + 31) / 32;
    const int nbA8 = (int)(((size_t)n * 8 + 255) / 256);

    hist_kernel<<<NEB + 48, 256, 0, stream>>>(col, H, E, NBKT, W1, W2, WT1, WT2, NEB);
    rowscan_kernel<<<NBKT, 512, 0, stream>>>(H, rowSum, NEB, NBKT);
    scatter_gemm_kernel<<<NEB + nbG, 256, 0, stream>>>(
        row, col, eattr, H, rowSum, sedge1, E, NBKT, NEB, x, WT1, g1, n);
    fine_dinv_kernel<<<NBKT, 512, 0, stream>>>(sedge1, rowSum, nodeStart, nodeCnt,
                                               dinv, n, NBKT);
    fine_csr_kernel<<<NBKT, 512, 0, stream>>>(sedge1, rowSum, nodeStart, dinv,
                                              sedge2, n, NBKT);

    aggmm_kernel<<<nbG2, 256, 0, stream>>>(g1, sedge2, nodeStart, nodeCnt, dinv, b1, WT2, g2, n);
    agg_kernel<<<nbA8, 256, 0, stream>>>(g2, sedge2, nodeStart, nodeCnt, dinv, b2, out, n);
}